// Round 11
// baseline (636.825 us; speedup 1.0000x reference)
//
#include <hip/hip_runtime.h>
#include <hip/hip_bf16.h>

#define DEVINL __device__ __forceinline__

constexpr int N  = 50000;
constexpr int E  = 600000;
constexpr int TE = E + N;      // edges + self loops
constexpr int D  = 128;
constexpr int SCAN_B = (N + 255) / 256;   // 196 blocks for hierarchical scan
constexpr int GEMM_ROWS = 64;             // 16 rows per wave, 4 waves
constexpr int GEMM_B = (N + GEMM_ROWS - 1) / GEMM_ROWS;  // 782

typedef short bf16x8 __attribute__((ext_vector_type(8)));
typedef float f32x4  __attribute__((ext_vector_type(4)));

DEVINL float lrelu(float x, float s) { return x >= 0.f ? x : s * x; }

DEVINL unsigned short f2bf(float f) {   // RNE fp32 -> bf16
    unsigned u = __float_as_uint(f);
    u += 0x7FFFu + ((u >> 16) & 1u);
    return (unsigned short)(u >> 16);
}

// ---------- W -> bf16 copy for all 3 layers (layout unchanged: Wb[o][k]) ----------
__global__ __launch_bounds__(256) void k_wb3(const float* __restrict__ W0,
                                             const float* __restrict__ W1,
                                             const float* __restrict__ W2,
                                             unsigned short* __restrict__ Wb) {
    int b = blockIdx.x;          // 192 blocks: 64 per layer
    int l = b >> 6;
    const float* W = (l == 0) ? W0 : (l == 1) ? W1 : W2;
    int t = (b & 63) * 256 + threadIdx.x;   // 0..16383
    Wb[l * 16384 + t] = f2bf(W[t]);
}

// ---------- MFMA GEMM: H[v,o] = sum_k Xbn[v,k] * W[o,k]  (bf16 inputs, fp32 acc) ----------
__global__ __launch_bounds__(256) void k_gemm(const float* __restrict__ X,
                                              const unsigned short* __restrict__ Wb,
                                              unsigned short* __restrict__ Hb16,
                                              const float* __restrict__ att,
                                              float* __restrict__ ai,
                                              float* __restrict__ aj,
                                              const float* __restrict__ ss, // scale[128], shift[128]
                                              int apply_bn) {
    int wave = threadIdx.x >> 6, lane = threadIdx.x & 63;
    int m = lane & 15, quad = lane >> 4;
    int r0 = blockIdx.x * GEMM_ROWS + wave * 16;

    // ---- A fragments for 4 K-steps ----
    bf16x8 afrag[4];
    int rowA = r0 + m;
    bool rowok = rowA < N;
    #pragma unroll
    for (int k4 = 0; k4 < 4; k4++) {
        int c0 = k4 * 32 + quad * 8;   // feature column of first element
        float v[8];
        if (rowok) {
            float4 x0 = *(const float4*)(X + (size_t)rowA * D + c0);
            float4 x1 = *(const float4*)(X + (size_t)rowA * D + c0 + 4);
            v[0] = x0.x; v[1] = x0.y; v[2] = x0.z; v[3] = x0.w;
            v[4] = x1.x; v[5] = x1.y; v[6] = x1.z; v[7] = x1.w;
            if (apply_bn) {
                #pragma unroll
                for (int j = 0; j < 8; j++)
                    v[j] = lrelu(v[j] * ss[c0 + j] + ss[128 + c0 + j], 0.1f);
            }
        } else {
            #pragma unroll
            for (int j = 0; j < 8; j++) v[j] = 0.f;
        }
        #pragma unroll
        for (int j = 0; j < 8; j++) afrag[k4][j] = (short)f2bf(v[j]);
    }

    // ---- 8 col-tiles of 16, K=128 via 4 MFMA each ----
    float pii[4] = {0.f, 0.f, 0.f, 0.f};
    float pjj[4] = {0.f, 0.f, 0.f, 0.f};
    #pragma unroll
    for (int nt = 0; nt < 8; nt++) {
        int n0 = nt * 16;
        f32x4 acc = {0.f, 0.f, 0.f, 0.f};
        const unsigned short* wrow = Wb + (size_t)(n0 + m) * D + quad * 8;
        #pragma unroll
        for (int k4 = 0; k4 < 4; k4++) {
            bf16x8 b = *(const bf16x8*)(wrow + k4 * 32);
            acc = __builtin_amdgcn_mfma_f32_16x16x32_bf16(afrag[k4], b, acc, 0, 0, 0);
        }
        float ad = att[n0 + m];
        float as = att[128 + n0 + m];
        #pragma unroll
        for (int i = 0; i < 4; i++) {
            int row = r0 + quad * 4 + i;
            if (row < N) Hb16[(size_t)row * D + n0 + m] = f2bf(acc[i]);
            pii[i] += acc[i] * ad;
            pjj[i] += acc[i] * as;
        }
    }

    // ---- reduce attention dots across the 16 lanes of each quad ----
    #pragma unroll
    for (int mask = 8; mask >= 1; mask >>= 1) {
        #pragma unroll
        for (int i = 0; i < 4; i++) {
            pii[i] += __shfl_xor(pii[i], mask);
            pjj[i] += __shfl_xor(pjj[i], mask);
        }
    }
    if (m == 0) {
        #pragma unroll
        for (int i = 0; i < 4; i++) {
            int row = r0 + quad * 4 + i;
            if (row < N) { ai[row] = pii[i]; aj[row] = pjj[i]; }
        }
    }
}

DEVINL void edge_sd(int e, const int* ei, int& s, int& d) {
    if (e < E) { s = ei[e]; d = ei[E + e]; }
    else       { s = d = e - E; }
}

// ---------- CSR build by dst (once; graph shared across layers) ----------
__global__ __launch_bounds__(256) void k_deg(const int* __restrict__ ei, int* __restrict__ deg) {
    int e = blockIdx.x * 256 + threadIdx.x;
    if (e >= TE) return;
    int s, d; edge_sd(e, ei, s, d);
    atomicAdd(deg + d, 1);
}

__global__ __launch_bounds__(256) void k_scan1(const int* __restrict__ deg, int* __restrict__ bsum) {
    __shared__ int red[256];
    int t = threadIdx.x;
    int v = blockIdx.x * 256 + t;
    red[t] = (v < N) ? deg[v] : 0;
    __syncthreads();
    #pragma unroll
    for (int off = 128; off; off >>= 1) {
        if (t < off) red[t] += red[t + off];
        __syncthreads();
    }
    if (t == 0) bsum[blockIdx.x] = red[0];
}

__global__ __launch_bounds__(256) void k_scan2(const int* __restrict__ bsum,
                                               int* __restrict__ boff, int* __restrict__ row_ptr) {
    __shared__ int sc[256];
    int t = threadIdx.x;
    int v = (t < SCAN_B) ? bsum[t] : 0;
    sc[t] = v;
    __syncthreads();
    #pragma unroll
    for (int off = 1; off < 256; off <<= 1) {
        int add = (t >= off) ? sc[t - off] : 0;
        __syncthreads();
        sc[t] += add;
        __syncthreads();
    }
    if (t < SCAN_B) boff[t] = sc[t] - v;       // exclusive
    if (t == SCAN_B - 1) row_ptr[N] = sc[t];   // total = TE
}

__global__ __launch_bounds__(256) void k_scan3(const int* __restrict__ deg,
                                               const int* __restrict__ boff,
                                               int* __restrict__ row_ptr) {
    __shared__ int sc[256];
    int t = threadIdx.x;
    int v = blockIdx.x * 256 + t;
    int d = (v < N) ? deg[v] : 0;
    sc[t] = d;
    __syncthreads();
    #pragma unroll
    for (int off = 1; off < 256; off <<= 1) {
        int add = (t >= off) ? sc[t - off] : 0;
        __syncthreads();
        sc[t] += add;
        __syncthreads();
    }
    if (v < N) row_ptr[v] = boff[blockIdx.x] + sc[t] - d;
}

// ---------- fill: only src_csr (dst implied by CSR row) ----------
__global__ __launch_bounds__(256) void k_fill(const int* __restrict__ ei,
                                              const int* __restrict__ row_ptr,
                                              int* __restrict__ fill,
                                              int* __restrict__ src_csr) {
    int e = blockIdx.x * 256 + threadIdx.x;
    if (e >= TE) return;
    int s, d; edge_sd(e, ei, s, d);
    int pos = atomicAdd(fill + d, 1);
    src_csr[row_ptr[d] + pos] = s;
}

// ---------- per-edge softmax numerator + denominator, 16-lane group per dst node ----------
// (wave-per-node wasted ~80% of lanes at mean degree ~13)
__global__ __launch_bounds__(256) void k_edge_soft(const int* __restrict__ row_ptr,
                                                   const int* __restrict__ src_csr,
                                                   const float* __restrict__ ai,
                                                   const float* __restrict__ aj,
                                                   float* __restrict__ alpha,
                                                   float* __restrict__ den) {
    int g = threadIdx.x >> 4, l16 = threadIdx.x & 15;
    int v = blockIdx.x * 16 + g;
    if (v >= N) return;
    int beg = row_ptr[v], end = row_ptr[v + 1];
    float aiv = ai[v];                       // dst-side dot, group-uniform
    for (int idx = beg + l16; idx < end; idx += 16) {
        int s = src_csr[idx];
        float a  = lrelu(aiv + aj[s], 0.2f);
        float ex = expf(a);
        alpha[idx] = ex;
        atomicAdd(den + s, ex);
    }
}

// ---------- per-node reciprocal of denominator ----------
__global__ __launch_bounds__(256) void k_invden(const float* __restrict__ den,
                                                float* __restrict__ invden) {
    int v = blockIdx.x * 256 + threadIdx.x;
    if (v >= N) return;
    invden[v] = 1.0f / (den[v] + 1e-16f);
}

// ---------- aggregation: wave per dst node, 8-edge unroll + scalar tail, bf16 H gather ----------
// NOTE: predicated/clamped 8-slot variant measured WORSE (66 vs 43.5 us, R9) —
// dependent cndmask before each gather + duplicated pad gathers kill MLP. Keep this form.
__global__ __launch_bounds__(256) void k_aggregate(const int* __restrict__ row_ptr,
                                                   const int* __restrict__ src_csr,
                                                   const float* __restrict__ alpha,
                                                   const float* __restrict__ invden,
                                                   const unsigned* __restrict__ Hu, // bf16x2 per uint
                                                   const float* __restrict__ bvec,
                                                   float* __restrict__ O) {
    int wid = threadIdx.x >> 6, lane = threadIdx.x & 63;
    int v = blockIdx.x * 4 + wid;
    if (v >= N) return;
    int beg = row_ptr[v], end = row_ptr[v + 1];
    float a0 = 0.f, a1 = 0.f;
    int idx = beg;
    for (; idx + 8 <= end; idx += 8) {
        int      s[8];
        float    w[8];
        unsigned u[8];
        #pragma unroll
        for (int t = 0; t < 8; t++) s[t] = src_csr[idx + t];
        #pragma unroll
        for (int t = 0; t < 8; t++) w[t] = alpha[idx + t] * invden[s[t]];
        #pragma unroll
        for (int t = 0; t < 8; t++) u[t] = Hu[(size_t)s[t] * 64 + lane];
        #pragma unroll
        for (int t = 0; t < 8; t++) {
            a0 += w[t] * __uint_as_float(u[t] << 16);
            a1 += w[t] * __uint_as_float(u[t] & 0xFFFF0000u);
        }
    }
    for (; idx < end; idx++) {
        int s = src_csr[idx];
        float w = alpha[idx] * invden[s];
        unsigned u = Hu[(size_t)s * 64 + lane];
        a0 += w * __uint_as_float(u << 16);
        a1 += w * __uint_as_float(u & 0xFFFF0000u);
    }
    float2 b = ((const float2*)bvec)[lane];
    a0 = fmaxf(a0 + b.x, 0.f);
    a1 = fmaxf(a1 + b.y, 0.f);
    ((float2*)(O + (size_t)v * D))[lane] = make_float2(a0, a1);
}

// ---------- BN column stats + fused finalize (last-block pattern) ----------
__global__ __launch_bounds__(256) void k_stats(const float* __restrict__ O,
                                               float* __restrict__ colsum,
                                               float* __restrict__ colsq,
                                               int* __restrict__ ctr,
                                               const float* __restrict__ g,
                                               const float* __restrict__ be,
                                               float* __restrict__ ss) {
    int c = threadIdx.x & 127, rg = threadIdx.x >> 7;
    float s = 0.f, q = 0.f;
    for (int v = blockIdx.x * 2 + rg; v < N; v += gridDim.x * 2) {
        float val = O[(size_t)v * D + c];
        s += val;
        q += val * val;
    }
    __shared__ float ls[256], lq[256];
    ls[threadIdx.x] = s; lq[threadIdx.x] = q;
    __syncthreads();
    if (threadIdx.x < 128) {
        s = ls[threadIdx.x] + ls[threadIdx.x + 128];
        q = lq[threadIdx.x] + lq[threadIdx.x + 128];
        atomicAdd(colsum + c, s);
        atomicAdd(colsq + c, q);
    }
    // last block finalizes scale/shift (saves the separate k_bnfinal launch)
    __threadfence();
    __syncthreads();
    __shared__ int isLast;
    if (threadIdx.x == 0)
        isLast = (atomicAdd(ctr, 1) == (int)gridDim.x - 1);
    __syncthreads();
    if (isLast && threadIdx.x < 128) {
        int cc = threadIdx.x;
        float cs = __hip_atomic_load(colsum + cc, __ATOMIC_RELAXED, __HIP_MEMORY_SCOPE_AGENT);
        float cq = __hip_atomic_load(colsq  + cc, __ATOMIC_RELAXED, __HIP_MEMORY_SCOPE_AGENT);
        float mean = cs / (float)N;
        float var  = cq / (float)N - mean * mean;
        float scale = g[cc] * rsqrtf(var + 1e-5f);
        ss[cc] = scale;
        ss[128 + cc] = be[cc] - mean * scale;
    }
}

// ---------- decoder ----------
__global__ __launch_bounds__(256) void k_T(const float* __restrict__ P1, const float* __restrict__ P2,
                                           float* __restrict__ T) {
    int t = blockIdx.x * 256 + threadIdx.x;
    if (t >= 128 * 64) return;
    int i = t >> 6, d = t & 63;
    float s = 0.f;
    #pragma unroll 8
    for (int k = 0; k < 64; k++) s += P1[i * 64 + k] * P2[k * 64 + d];
    T[t] = s;
}

__global__ __launch_bounds__(256) void k_M(const float* __restrict__ T, const float* __restrict__ P1,
                                           float* __restrict__ M) {
    int t = blockIdx.x * 256 + threadIdx.x;
    if (t >= 128 * 128) return;
    int i = t >> 7, j = t & 127;
    float s = 0.f;
    #pragma unroll 8
    for (int d = 0; d < 64; d++) s += T[i * 64 + d] * P1[j * 64 + d];
    M[t] = s;
}

__global__ __launch_bounds__(128) void k_pred(const float* __restrict__ O,
                                              const float* __restrict__ ss,
                                              const int* __restrict__ drug,
                                              const float* __restrict__ M,
                                              float* __restrict__ out) {
    int b = blockIdx.x, i = threadIdx.x;
    __shared__ float av[128], bv[128];
    int ia = drug[b * 2] - 1, ib = drug[b * 2 + 1] - 1;
    float sc = ss[i], sh = ss[128 + i];
    av[i] = lrelu(O[(size_t)ia * D + i] * sc + sh, 0.1f);
    bv[i] = lrelu(O[(size_t)ib * D + i] * sc + sh, 0.1f);
    __syncthreads();
    float u = 0.f;
    #pragma unroll 8
    for (int j = 0; j < 128; j++) u += M[i * 128 + j] * bv[j];
    float val = av[i] * u;
    #pragma unroll
    for (int off = 32; off; off >>= 1) val += __shfl_down(val, off);
    __shared__ float red[2];
    if ((i & 63) == 0) red[i >> 6] = val;
    __syncthreads();
    if (i == 0) out[b] = red[0] + red[1];
}

extern "C" void kernel_launch(void* const* d_in, const int* in_sizes, int n_in,
                              void* d_out, int out_size, void* d_ws, size_t ws_size,
                              hipStream_t stream) {
    const float* x    = (const float*)d_in[0];
    const int*   ei   = (const int*)  d_in[1];
    const int*   drug = (const int*)  d_in[2];
    const float* W[3]   = {(const float*)d_in[3], (const float*)d_in[8],  (const float*)d_in[13]};
    const float* att[3] = {(const float*)d_in[4], (const float*)d_in[9],  (const float*)d_in[14]};
    const float* bb[3]  = {(const float*)d_in[5], (const float*)d_in[10], (const float*)d_in[15]};
    const float* gg[3]  = {(const float*)d_in[6], (const float*)d_in[11], (const float*)d_in[16]};
    const float* be[3]  = {(const float*)d_in[7], (const float*)d_in[12], (const float*)d_in[17]};
    const float* P1 = (const float*)d_in[18];
    const float* P2 = (const float*)d_in[19];

    float* ws = (float*)d_ws;
    size_t o_H      = 0;                     // bf16 H: N*D ushorts = N*64 floats
    size_t o_O      = o_H + (size_t)N * 64;
    size_t o_ai     = o_O + (size_t)N * D;
    size_t o_aj     = o_ai + N;
    size_t o_den    = o_aj + N;
    size_t o_inv    = o_den + N;
    size_t o_alpha  = o_inv + N;
    size_t o_deg    = o_alpha + TE;    // int
    size_t o_fill   = o_deg + N;       // int
    size_t o_rowptr = o_fill + N;      // int, N+1 (pad 8)
    size_t o_src    = o_rowptr + N + 8;// int, TE
    size_t o_bsum   = o_src + TE;      // int, SCAN_B (pad to 256)
    size_t o_boff   = o_bsum + 256;    // int, SCAN_B (pad to 256)
    size_t o_colsum = o_boff + 256;    // 128
    size_t o_colsq  = o_colsum + 128;  // 128
    size_t o_ctr    = o_colsq + 128;   // 8 (int counter, zeroed with colsum/colsq)
    size_t o_ss     = o_ctr + 8;       // 256
    size_t o_T      = o_ss + 256;      // 128*64
    size_t o_Mm     = o_T + 128 * 64;  // 128*128
    size_t o_Wb     = o_Mm + 128 * 128;// 3*16384 ushorts = 24576 floats

    unsigned short* Hb16 = (unsigned short*)(ws + o_H);
    unsigned*       Hu   = (unsigned*)(ws + o_H);
    float*    Ob    = ws + o_O;
    float*    ai    = ws + o_ai;
    float*    aj    = ws + o_aj;
    float*    den   = ws + o_den;
    float*    inv   = ws + o_inv;
    float*    alpha = ws + o_alpha;
    int*      deg   = (int*)(ws + o_deg);
    int*      fill  = (int*)(ws + o_fill);
    int*      rowp  = (int*)(ws + o_rowptr);
    int*      srcc  = (int*)(ws + o_src);
    int*      bsum  = (int*)(ws + o_bsum);
    int*      boff  = (int*)(ws + o_boff);
    float*    csum  = ws + o_colsum;
    float*    csq   = ws + o_colsq;
    int*      ctr   = (int*)(ws + o_ctr);
    float*    ss    = ws + o_ss;
    float*    Tm    = ws + o_T;
    float*    Mm    = ws + o_Mm;
    unsigned short* Wb = (unsigned short*)(ws + o_Wb);

    const int EB = (TE + 255) / 256;
    const int NB4  = (N + 3) / 4;
    const int NB16 = (N + 15) / 16;

    // ---- CSR by dst ----
    hipMemsetAsync(deg, 0, (size_t)N * 4, stream);
    k_deg<<<EB, 256, 0, stream>>>(ei, deg);
    k_scan1<<<SCAN_B, 256, 0, stream>>>(deg, bsum);
    k_scan2<<<1, 256, 0, stream>>>(bsum, boff, rowp);
    k_scan3<<<SCAN_B, 256, 0, stream>>>(deg, boff, rowp);
    hipMemsetAsync(fill, 0, (size_t)N * 4, stream);
    k_fill<<<EB, 256, 0, stream>>>(ei, rowp, fill, srcc);

    // ---- W bf16 copies (one launch) ----
    k_wb3<<<192, 256, 0, stream>>>(W[0], W[1], W[2], Wb);

    // ---- 3 GAT layers ----
    for (int l = 0; l < 3; l++) {
        const float* Xin = (l == 0) ? x : Ob;
        k_gemm<<<GEMM_B, 256, 0, stream>>>(Xin, Wb + l * 16384, Hb16, att[l], ai, aj, ss, l > 0 ? 1 : 0);
        hipMemsetAsync(den, 0, (size_t)N * 4, stream);
        k_edge_soft<<<NB16, 256, 0, stream>>>(rowp, srcc, ai, aj, alpha, den);
        k_invden<<<SCAN_B, 256, 0, stream>>>(den, inv);
        k_aggregate<<<NB4, 256, 0, stream>>>(rowp, srcc, alpha, inv, Hu, bb[l], Ob);
        hipMemsetAsync(csum, 0, 264 * 4, stream);            // colsum + colsq + ctr
        k_stats<<<256, 256, 0, stream>>>(Ob, csum, csq, ctr, gg[l], be[l], ss);
    }

    // ---- decoder ----
    k_T<<<32, 256, 0, stream>>>(P1, P2, Tm);
    k_M<<<64, 256, 0, stream>>>(Tm, P1, Mm);
    k_pred<<<1024, 128, 0, stream>>>(Ob, ss, drug, Mm, (float*)d_out);
}

// Round 12
// 556.602 us; speedup vs baseline: 1.1441x; 1.1441x over previous
//
#include <hip/hip_runtime.h>
#include <hip/hip_bf16.h>

#define DEVINL __device__ __forceinline__

constexpr int N  = 50000;
constexpr int E  = 600000;
constexpr int TE = E + N;      // edges + self loops
constexpr int D  = 128;
constexpr int SCAN_B = (N + 255) / 256;   // 196 blocks for hierarchical scan
constexpr int GEMM_ROWS = 64;             // 16 rows per wave, 4 waves
constexpr int GEMM_B = (N + GEMM_ROWS - 1) / GEMM_ROWS;  // 782

typedef short bf16x8 __attribute__((ext_vector_type(8)));
typedef float f32x4  __attribute__((ext_vector_type(4)));

DEVINL float lrelu(float x, float s) { return x >= 0.f ? x : s * x; }

DEVINL unsigned short f2bf(float f) {   // RNE fp32 -> bf16
    unsigned u = __float_as_uint(f);
    u += 0x7FFFu + ((u >> 16) & 1u);
    return (unsigned short)(u >> 16);
}

// ---------- W -> bf16 copy for all 3 layers (layout unchanged: Wb[o][k]) ----------
__global__ __launch_bounds__(256) void k_wb3(const float* __restrict__ W0,
                                             const float* __restrict__ W1,
                                             const float* __restrict__ W2,
                                             unsigned short* __restrict__ Wb) {
    int b = blockIdx.x;          // 192 blocks: 64 per layer
    int l = b >> 6;
    const float* W = (l == 0) ? W0 : (l == 1) ? W1 : W2;
    int t = (b & 63) * 256 + threadIdx.x;   // 0..16383
    Wb[l * 16384 + t] = f2bf(W[t]);
}

// ---------- MFMA GEMM: H[v,o] = sum_k Xbn[v,k] * W[o,k]  (bf16 inputs, fp32 acc) ----------
__global__ __launch_bounds__(256) void k_gemm(const float* __restrict__ X,
                                              const unsigned short* __restrict__ Wb,
                                              unsigned short* __restrict__ Hb16,
                                              const float* __restrict__ att,
                                              float* __restrict__ ai,
                                              float* __restrict__ aj,
                                              const float* __restrict__ ss, // scale[128], shift[128]
                                              int apply_bn) {
    int wave = threadIdx.x >> 6, lane = threadIdx.x & 63;
    int m = lane & 15, quad = lane >> 4;
    int r0 = blockIdx.x * GEMM_ROWS + wave * 16;

    // ---- A fragments for 4 K-steps ----
    bf16x8 afrag[4];
    int rowA = r0 + m;
    bool rowok = rowA < N;
    #pragma unroll
    for (int k4 = 0; k4 < 4; k4++) {
        int c0 = k4 * 32 + quad * 8;   // feature column of first element
        float v[8];
        if (rowok) {
            float4 x0 = *(const float4*)(X + (size_t)rowA * D + c0);
            float4 x1 = *(const float4*)(X + (size_t)rowA * D + c0 + 4);
            v[0] = x0.x; v[1] = x0.y; v[2] = x0.z; v[3] = x0.w;
            v[4] = x1.x; v[5] = x1.y; v[6] = x1.z; v[7] = x1.w;
            if (apply_bn) {
                #pragma unroll
                for (int j = 0; j < 8; j++)
                    v[j] = lrelu(v[j] * ss[c0 + j] + ss[128 + c0 + j], 0.1f);
            }
        } else {
            #pragma unroll
            for (int j = 0; j < 8; j++) v[j] = 0.f;
        }
        #pragma unroll
        for (int j = 0; j < 8; j++) afrag[k4][j] = (short)f2bf(v[j]);
    }

    // ---- 8 col-tiles of 16, K=128 via 4 MFMA each ----
    float pii[4] = {0.f, 0.f, 0.f, 0.f};
    float pjj[4] = {0.f, 0.f, 0.f, 0.f};
    #pragma unroll
    for (int nt = 0; nt < 8; nt++) {
        int n0 = nt * 16;
        f32x4 acc = {0.f, 0.f, 0.f, 0.f};
        const unsigned short* wrow = Wb + (size_t)(n0 + m) * D + quad * 8;
        #pragma unroll
        for (int k4 = 0; k4 < 4; k4++) {
            bf16x8 b = *(const bf16x8*)(wrow + k4 * 32);
            acc = __builtin_amdgcn_mfma_f32_16x16x32_bf16(afrag[k4], b, acc, 0, 0, 0);
        }
        float ad = att[n0 + m];
        float as = att[128 + n0 + m];
        #pragma unroll
        for (int i = 0; i < 4; i++) {
            int row = r0 + quad * 4 + i;
            if (row < N) Hb16[(size_t)row * D + n0 + m] = f2bf(acc[i]);
            pii[i] += acc[i] * ad;
            pjj[i] += acc[i] * as;
        }
    }

    // ---- reduce attention dots across the 16 lanes of each quad ----
    #pragma unroll
    for (int mask = 8; mask >= 1; mask >>= 1) {
        #pragma unroll
        for (int i = 0; i < 4; i++) {
            pii[i] += __shfl_xor(pii[i], mask);
            pjj[i] += __shfl_xor(pjj[i], mask);
        }
    }
    if (m == 0) {
        #pragma unroll
        for (int i = 0; i < 4; i++) {
            int row = r0 + quad * 4 + i;
            if (row < N) { ai[row] = pii[i]; aj[row] = pjj[i]; }
        }
    }
}

DEVINL void edge_sd(int e, const int* ei, int& s, int& d) {
    if (e < E) { s = ei[e]; d = ei[E + e]; }
    else       { s = d = e - E; }
}

// ---------- CSR build by dst (once; graph shared across layers) ----------
__global__ __launch_bounds__(256) void k_deg(const int* __restrict__ ei, int* __restrict__ deg) {
    int e = blockIdx.x * 256 + threadIdx.x;
    if (e >= TE) return;
    int s, d; edge_sd(e, ei, s, d);
    atomicAdd(deg + d, 1);
}

__global__ __launch_bounds__(256) void k_scan1(const int* __restrict__ deg, int* __restrict__ bsum) {
    __shared__ int red[256];
    int t = threadIdx.x;
    int v = blockIdx.x * 256 + t;
    red[t] = (v < N) ? deg[v] : 0;
    __syncthreads();
    #pragma unroll
    for (int off = 128; off; off >>= 1) {
        if (t < off) red[t] += red[t + off];
        __syncthreads();
    }
    if (t == 0) bsum[blockIdx.x] = red[0];
}

__global__ __launch_bounds__(256) void k_scan2(const int* __restrict__ bsum,
                                               int* __restrict__ boff, int* __restrict__ row_ptr) {
    __shared__ int sc[256];
    int t = threadIdx.x;
    int v = (t < SCAN_B) ? bsum[t] : 0;
    sc[t] = v;
    __syncthreads();
    #pragma unroll
    for (int off = 1; off < 256; off <<= 1) {
        int add = (t >= off) ? sc[t - off] : 0;
        __syncthreads();
        sc[t] += add;
        __syncthreads();
    }
    if (t < SCAN_B) boff[t] = sc[t] - v;       // exclusive
    if (t == SCAN_B - 1) row_ptr[N] = sc[t];   // total = TE
}

__global__ __launch_bounds__(256) void k_scan3(const int* __restrict__ deg,
                                               const int* __restrict__ boff,
                                               int* __restrict__ row_ptr) {
    __shared__ int sc[256];
    int t = threadIdx.x;
    int v = blockIdx.x * 256 + t;
    int d = (v < N) ? deg[v] : 0;
    sc[t] = d;
    __syncthreads();
    #pragma unroll
    for (int off = 1; off < 256; off <<= 1) {
        int add = (t >= off) ? sc[t - off] : 0;
        __syncthreads();
        sc[t] += add;
        __syncthreads();
    }
    if (v < N) row_ptr[v] = boff[blockIdx.x] + sc[t] - d;
}

// ---------- fill: only src_csr (dst implied by CSR row) ----------
__global__ __launch_bounds__(256) void k_fill(const int* __restrict__ ei,
                                              const int* __restrict__ row_ptr,
                                              int* __restrict__ fill,
                                              int* __restrict__ src_csr) {
    int e = blockIdx.x * 256 + threadIdx.x;
    if (e >= TE) return;
    int s, d; edge_sd(e, ei, s, d);
    int pos = atomicAdd(fill + d, 1);
    src_csr[row_ptr[d] + pos] = s;
}

// ---------- per-edge softmax numerator + denominator, 16-lane group per dst node ----------
__global__ __launch_bounds__(256) void k_edge_soft(const int* __restrict__ row_ptr,
                                                   const int* __restrict__ src_csr,
                                                   const float* __restrict__ ai,
                                                   const float* __restrict__ aj,
                                                   float* __restrict__ alpha,
                                                   float* __restrict__ den) {
    int g = threadIdx.x >> 4, l16 = threadIdx.x & 15;
    int v = blockIdx.x * 16 + g;
    if (v >= N) return;
    int beg = row_ptr[v], end = row_ptr[v + 1];
    float aiv = ai[v];                       // dst-side dot, group-uniform
    for (int idx = beg + l16; idx < end; idx += 16) {
        int s = src_csr[idx];
        float a  = lrelu(aiv + aj[s], 0.2f);
        float ex = expf(a);
        alpha[idx] = ex;
        atomicAdd(den + s, ex);
    }
}

// ---------- per-node reciprocal of denominator ----------
__global__ __launch_bounds__(256) void k_invden(const float* __restrict__ den,
                                                float* __restrict__ invden) {
    int v = blockIdx.x * 256 + threadIdx.x;
    if (v >= N) return;
    invden[v] = 1.0f / (den[v] + 1e-16f);
}

// ---------- aggregation: wave per dst node, 8-edge unroll + scalar tail, bf16 H gather ----------
// NOTE: predicated/clamped 8-slot variant measured WORSE (66 vs 43.5 us, R9).
__global__ __launch_bounds__(256) void k_aggregate(const int* __restrict__ row_ptr,
                                                   const int* __restrict__ src_csr,
                                                   const float* __restrict__ alpha,
                                                   const float* __restrict__ invden,
                                                   const unsigned* __restrict__ Hu, // bf16x2 per uint
                                                   const float* __restrict__ bvec,
                                                   float* __restrict__ O) {
    int wid = threadIdx.x >> 6, lane = threadIdx.x & 63;
    int v = blockIdx.x * 4 + wid;
    if (v >= N) return;
    int beg = row_ptr[v], end = row_ptr[v + 1];
    float a0 = 0.f, a1 = 0.f;
    int idx = beg;
    for (; idx + 8 <= end; idx += 8) {
        int      s[8];
        float    w[8];
        unsigned u[8];
        #pragma unroll
        for (int t = 0; t < 8; t++) s[t] = src_csr[idx + t];
        #pragma unroll
        for (int t = 0; t < 8; t++) w[t] = alpha[idx + t] * invden[s[t]];
        #pragma unroll
        for (int t = 0; t < 8; t++) u[t] = Hu[(size_t)s[t] * 64 + lane];
        #pragma unroll
        for (int t = 0; t < 8; t++) {
            a0 += w[t] * __uint_as_float(u[t] << 16);
            a1 += w[t] * __uint_as_float(u[t] & 0xFFFF0000u);
        }
    }
    for (; idx < end; idx++) {
        int s = src_csr[idx];
        float w = alpha[idx] * invden[s];
        unsigned u = Hu[(size_t)s * 64 + lane];
        a0 += w * __uint_as_float(u << 16);
        a1 += w * __uint_as_float(u & 0xFFFF0000u);
    }
    float2 b = ((const float2*)bvec)[lane];
    a0 = fmaxf(a0 + b.x, 0.f);
    a1 = fmaxf(a1 + b.y, 0.f);
    ((float2*)(O + (size_t)v * D))[lane] = make_float2(a0, a1);
}

// ---------- BN column stats: float4 per thread, 8 row-groups, LDS reduce, no fences ----------
// NOTE (R11): last-block finalize via __threadfence() cost ~35 us/layer on gfx950
// (device-scope fence = per-XCD L2 writeback per block). Keep bnfinal as its own launch.
__global__ __launch_bounds__(256) void k_stats(const float* __restrict__ O,
                                               float* __restrict__ colsum, float* __restrict__ colsq) {
    int c4 = (threadIdx.x & 31) * 4;   // column base (4 cols per thread)
    int rg = threadIdx.x >> 5;         // row group 0..7
    float s0=0.f,s1=0.f,s2=0.f,s3=0.f,q0=0.f,q1=0.f,q2=0.f,q3=0.f;
    for (int v = blockIdx.x * 8 + rg; v < N; v += gridDim.x * 8) {
        float4 val = *(const float4*)(O + (size_t)v * D + c4);
        s0 += val.x; q0 += val.x * val.x;
        s1 += val.y; q1 += val.y * val.y;
        s2 += val.z; q2 += val.z * val.z;
        s3 += val.w; q3 += val.w * val.w;
    }
    __shared__ float ls[8][128], lq[8][128];   // 8 KB
    ls[rg][c4+0]=s0; ls[rg][c4+1]=s1; ls[rg][c4+2]=s2; ls[rg][c4+3]=s3;
    lq[rg][c4+0]=q0; lq[rg][c4+1]=q1; lq[rg][c4+2]=q2; lq[rg][c4+3]=q3;
    __syncthreads();
    if (threadIdx.x < 128) {
        int c = threadIdx.x;
        float s = 0.f, q = 0.f;
        #pragma unroll
        for (int r = 0; r < 8; r++) { s += ls[r][c]; q += lq[r][c]; }
        atomicAdd(colsum + c, s);
        atomicAdd(colsq + c, q);
    }
}

__global__ __launch_bounds__(128) void k_bnfinal(const float* __restrict__ colsum,
                                                 const float* __restrict__ colsq,
                                                 const float* __restrict__ g,
                                                 const float* __restrict__ be,
                                                 float* __restrict__ ss) {
    int c = threadIdx.x;
    float mean = colsum[c] / (float)N;
    float var  = colsq[c] / (float)N - mean * mean;
    float scale = g[c] * rsqrtf(var + 1e-5f);
    ss[c] = scale;
    ss[128 + c] = be[c] - mean * scale;
}

// ---------- decoder ----------
__global__ __launch_bounds__(256) void k_T(const float* __restrict__ P1, const float* __restrict__ P2,
                                           float* __restrict__ T) {
    int t = blockIdx.x * 256 + threadIdx.x;
    if (t >= 128 * 64) return;
    int i = t >> 6, d = t & 63;
    float s = 0.f;
    #pragma unroll 8
    for (int k = 0; k < 64; k++) s += P1[i * 64 + k] * P2[k * 64 + d];
    T[t] = s;
}

__global__ __launch_bounds__(256) void k_M(const float* __restrict__ T, const float* __restrict__ P1,
                                           float* __restrict__ M) {
    int t = blockIdx.x * 256 + threadIdx.x;
    if (t >= 128 * 128) return;
    int i = t >> 7, j = t & 127;
    float s = 0.f;
    #pragma unroll 8
    for (int d = 0; d < 64; d++) s += T[i * 64 + d] * P1[j * 64 + d];
    M[t] = s;
}

__global__ __launch_bounds__(128) void k_pred(const float* __restrict__ O,
                                              const float* __restrict__ ss,
                                              const int* __restrict__ drug,
                                              const float* __restrict__ M,
                                              float* __restrict__ out) {
    int b = blockIdx.x, i = threadIdx.x;
    __shared__ float av[128], bv[128];
    int ia = drug[b * 2] - 1, ib = drug[b * 2 + 1] - 1;
    float sc = ss[i], sh = ss[128 + i];
    av[i] = lrelu(O[(size_t)ia * D + i] * sc + sh, 0.1f);
    bv[i] = lrelu(O[(size_t)ib * D + i] * sc + sh, 0.1f);
    __syncthreads();
    float u = 0.f;
    #pragma unroll 8
    for (int j = 0; j < 128; j++) u += M[i * 128 + j] * bv[j];
    float val = av[i] * u;
    #pragma unroll
    for (int off = 32; off; off >>= 1) val += __shfl_down(val, off);
    __shared__ float red[2];
    if ((i & 63) == 0) red[i >> 6] = val;
    __syncthreads();
    if (i == 0) out[b] = red[0] + red[1];
}

extern "C" void kernel_launch(void* const* d_in, const int* in_sizes, int n_in,
                              void* d_out, int out_size, void* d_ws, size_t ws_size,
                              hipStream_t stream) {
    const float* x    = (const float*)d_in[0];
    const int*   ei   = (const int*)  d_in[1];
    const int*   drug = (const int*)  d_in[2];
    const float* W[3]   = {(const float*)d_in[3], (const float*)d_in[8],  (const float*)d_in[13]};
    const float* att[3] = {(const float*)d_in[4], (const float*)d_in[9],  (const float*)d_in[14]};
    const float* bb[3]  = {(const float*)d_in[5], (const float*)d_in[10], (const float*)d_in[15]};
    const float* gg[3]  = {(const float*)d_in[6], (const float*)d_in[11], (const float*)d_in[16]};
    const float* be[3]  = {(const float*)d_in[7], (const float*)d_in[12], (const float*)d_in[17]};
    const float* P1 = (const float*)d_in[18];
    const float* P2 = (const float*)d_in[19];

    float* ws = (float*)d_ws;
    size_t o_H      = 0;                     // bf16 H: N*D ushorts = N*64 floats
    size_t o_O      = o_H + (size_t)N * 64;
    size_t o_ai     = o_O + (size_t)N * D;
    size_t o_aj     = o_ai + N;
    size_t o_den    = o_aj + N;
    size_t o_inv    = o_den + N;
    size_t o_alpha  = o_inv + N;
    size_t o_deg    = o_alpha + TE;    // int
    size_t o_fill   = o_deg + N;       // int
    size_t o_rowptr = o_fill + N;      // int, N+1 (pad 8)
    size_t o_src    = o_rowptr + N + 8;// int, TE
    size_t o_bsum   = o_src + TE;      // int, SCAN_B (pad to 256)
    size_t o_boff   = o_bsum + 256;    // int, SCAN_B (pad to 256)
    size_t o_colsum = o_boff + 256;    // 128
    size_t o_colsq  = o_colsum + 128;  // 128
    size_t o_ss     = o_colsq + 128;   // 256
    size_t o_T      = o_ss + 256;      // 128*64
    size_t o_Mm     = o_T + 128 * 64;  // 128*128
    size_t o_Wb     = o_Mm + 128 * 128;// 3*16384 ushorts = 24576 floats

    unsigned short* Hb16 = (unsigned short*)(ws + o_H);
    unsigned*       Hu   = (unsigned*)(ws + o_H);
    float*    Ob    = ws + o_O;
    float*    ai    = ws + o_ai;
    float*    aj    = ws + o_aj;
    float*    den   = ws + o_den;
    float*    inv   = ws + o_inv;
    float*    alpha = ws + o_alpha;
    int*      deg   = (int*)(ws + o_deg);
    int*      fill  = (int*)(ws + o_fill);
    int*      rowp  = (int*)(ws + o_rowptr);
    int*      srcc  = (int*)(ws + o_src);
    int*      bsum  = (int*)(ws + o_bsum);
    int*      boff  = (int*)(ws + o_boff);
    float*    csum  = ws + o_colsum;
    float*    csq   = ws + o_colsq;
    float*    ss    = ws + o_ss;
    float*    Tm    = ws + o_T;
    float*    Mm    = ws + o_Mm;
    unsigned short* Wb = (unsigned short*)(ws + o_Wb);

    const int EB = (TE + 255) / 256;
    const int NB4  = (N + 3) / 4;
    const int NB16 = (N + 15) / 16;

    // ---- CSR by dst ----
    hipMemsetAsync(deg, 0, (size_t)N * 4, stream);
    k_deg<<<EB, 256, 0, stream>>>(ei, deg);
    k_scan1<<<SCAN_B, 256, 0, stream>>>(deg, bsum);
    k_scan2<<<1, 256, 0, stream>>>(bsum, boff, rowp);
    k_scan3<<<SCAN_B, 256, 0, stream>>>(deg, boff, rowp);
    hipMemsetAsync(fill, 0, (size_t)N * 4, stream);
    k_fill<<<EB, 256, 0, stream>>>(ei, rowp, fill, srcc);

    // ---- W bf16 copies (one launch) ----
    k_wb3<<<192, 256, 0, stream>>>(W[0], W[1], W[2], Wb);

    // ---- 3 GAT layers ----
    for (int l = 0; l < 3; l++) {
        const float* Xin = (l == 0) ? x : Ob;
        k_gemm<<<GEMM_B, 256, 0, stream>>>(Xin, Wb + l * 16384, Hb16, att[l], ai, aj, ss, l > 0 ? 1 : 0);
        hipMemsetAsync(den, 0, (size_t)N * 4, stream);
        k_edge_soft<<<NB16, 256, 0, stream>>>(rowp, srcc, ai, aj, alpha, den);
        k_invden<<<SCAN_B, 256, 0, stream>>>(den, inv);
        k_aggregate<<<NB4, 256, 0, stream>>>(rowp, srcc, alpha, inv, Hu, bb[l], Ob);
        hipMemsetAsync(csum, 0, 256 * 4, stream);            // colsum + colsq
        k_stats<<<256, 256, 0, stream>>>(Ob, csum, csq);
        k_bnfinal<<<1, 128, 0, stream>>>(csum, csq, gg[l], be[l], ss);
    }

    // ---- decoder ----
    k_T<<<32, 256, 0, stream>>>(P1, P2, Tm);
    k_M<<<64, 256, 0, stream>>>(Tm, P1, Mm);
    k_pred<<<1024, 128, 0, stream>>>(Ob, ss, drug, Mm, (float*)d_out);
}

// Round 13
// 532.517 us; speedup vs baseline: 1.1959x; 1.0452x over previous
//
#include <hip/hip_runtime.h>
#include <hip/hip_bf16.h>

#define DEVINL __device__ __forceinline__

constexpr int N  = 50000;
constexpr int E  = 600000;
constexpr int TE = E + N;      // edges + self loops
constexpr int D  = 128;
constexpr int SCAN_B = (N + 255) / 256;   // 196 blocks for hierarchical scan
constexpr int GEMM_ROWS = 64;             // 16 rows per wave, 4 waves
constexpr int GEMM_B = (N + GEMM_ROWS - 1) / GEMM_ROWS;  // 782

typedef short bf16x8 __attribute__((ext_vector_type(8)));
typedef float f32x4  __attribute__((ext_vector_type(4)));

DEVINL float lrelu(float x, float s) { return x >= 0.f ? x : s * x; }

DEVINL unsigned short f2bf(float f) {   // RNE fp32 -> bf16
    unsigned u = __float_as_uint(f);
    u += 0x7FFFu + ((u >> 16) & 1u);
    return (unsigned short)(u >> 16);
}

// ---------- W -> bf16 copy for all 3 layers (layout unchanged: Wb[o][k]) ----------
__global__ __launch_bounds__(256) void k_wb3(const float* __restrict__ W0,
                                             const float* __restrict__ W1,
                                             const float* __restrict__ W2,
                                             unsigned short* __restrict__ Wb) {
    int b = blockIdx.x;          // 192 blocks: 64 per layer
    int l = b >> 6;
    const float* W = (l == 0) ? W0 : (l == 1) ? W1 : W2;
    int t = (b & 63) * 256 + threadIdx.x;   // 0..16383
    Wb[l * 16384 + t] = f2bf(W[t]);
}

// ---------- MFMA GEMM: H[v,o] = sum_k Xbn[v,k] * W[o,k]  (bf16 inputs, fp32 acc) ----------
__global__ __launch_bounds__(256) void k_gemm(const float* __restrict__ X,
                                              const unsigned short* __restrict__ Wb,
                                              unsigned short* __restrict__ Hb16,
                                              const float* __restrict__ att,
                                              float* __restrict__ ai,
                                              float* __restrict__ aj,
                                              const float* __restrict__ ss, // scale[128], shift[128]
                                              int apply_bn) {
    int wave = threadIdx.x >> 6, lane = threadIdx.x & 63;
    int m = lane & 15, quad = lane >> 4;
    int r0 = blockIdx.x * GEMM_ROWS + wave * 16;

    // ---- A fragments for 4 K-steps ----
    bf16x8 afrag[4];
    int rowA = r0 + m;
    bool rowok = rowA < N;
    #pragma unroll
    for (int k4 = 0; k4 < 4; k4++) {
        int c0 = k4 * 32 + quad * 8;   // feature column of first element
        float v[8];
        if (rowok) {
            float4 x0 = *(const float4*)(X + (size_t)rowA * D + c0);
            float4 x1 = *(const float4*)(X + (size_t)rowA * D + c0 + 4);
            v[0] = x0.x; v[1] = x0.y; v[2] = x0.z; v[3] = x0.w;
            v[4] = x1.x; v[5] = x1.y; v[6] = x1.z; v[7] = x1.w;
            if (apply_bn) {
                #pragma unroll
                for (int j = 0; j < 8; j++)
                    v[j] = lrelu(v[j] * ss[c0 + j] + ss[128 + c0 + j], 0.1f);
            }
        } else {
            #pragma unroll
            for (int j = 0; j < 8; j++) v[j] = 0.f;
        }
        #pragma unroll
        for (int j = 0; j < 8; j++) afrag[k4][j] = (short)f2bf(v[j]);
    }

    // ---- 8 col-tiles of 16, K=128 via 4 MFMA each ----
    float pii[4] = {0.f, 0.f, 0.f, 0.f};
    float pjj[4] = {0.f, 0.f, 0.f, 0.f};
    #pragma unroll
    for (int nt = 0; nt < 8; nt++) {
        int n0 = nt * 16;
        f32x4 acc = {0.f, 0.f, 0.f, 0.f};
        const unsigned short* wrow = Wb + (size_t)(n0 + m) * D + quad * 8;
        #pragma unroll
        for (int k4 = 0; k4 < 4; k4++) {
            bf16x8 b = *(const bf16x8*)(wrow + k4 * 32);
            acc = __builtin_amdgcn_mfma_f32_16x16x32_bf16(afrag[k4], b, acc, 0, 0, 0);
        }
        float ad = att[n0 + m];
        float as = att[128 + n0 + m];
        #pragma unroll
        for (int i = 0; i < 4; i++) {
            int row = r0 + quad * 4 + i;
            if (row < N) Hb16[(size_t)row * D + n0 + m] = f2bf(acc[i]);
            pii[i] += acc[i] * ad;
            pjj[i] += acc[i] * as;
        }
    }

    // ---- reduce attention dots across the 16 lanes of each quad ----
    #pragma unroll
    for (int mask = 8; mask >= 1; mask >>= 1) {
        #pragma unroll
        for (int i = 0; i < 4; i++) {
            pii[i] += __shfl_xor(pii[i], mask);
            pjj[i] += __shfl_xor(pjj[i], mask);
        }
    }
    if (m == 0) {
        #pragma unroll
        for (int i = 0; i < 4; i++) {
            int row = r0 + quad * 4 + i;
            if (row < N) { ai[row] = pii[i]; aj[row] = pjj[i]; }
        }
    }
}

DEVINL void edge_sd(int e, const int* ei, int& s, int& d) {
    if (e < E) { s = ei[e]; d = ei[E + e]; }
    else       { s = d = e - E; }
}

// ---------- CSR build by dst (once; graph shared across layers) ----------
__global__ __launch_bounds__(256) void k_deg(const int* __restrict__ ei, int* __restrict__ deg) {
    int e = blockIdx.x * 256 + threadIdx.x;
    if (e >= TE) return;
    int s, d; edge_sd(e, ei, s, d);
    atomicAdd(deg + d, 1);
}

__global__ __launch_bounds__(256) void k_scan1(const int* __restrict__ deg, int* __restrict__ bsum) {
    __shared__ int red[256];
    int t = threadIdx.x;
    int v = blockIdx.x * 256 + t;
    red[t] = (v < N) ? deg[v] : 0;
    __syncthreads();
    #pragma unroll
    for (int off = 128; off; off >>= 1) {
        if (t < off) red[t] += red[t + off];
        __syncthreads();
    }
    if (t == 0) bsum[blockIdx.x] = red[0];
}

__global__ __launch_bounds__(256) void k_scan2(const int* __restrict__ bsum,
                                               int* __restrict__ boff, int* __restrict__ row_ptr) {
    __shared__ int sc[256];
    int t = threadIdx.x;
    int v = (t < SCAN_B) ? bsum[t] : 0;
    sc[t] = v;
    __syncthreads();
    #pragma unroll
    for (int off = 1; off < 256; off <<= 1) {
        int add = (t >= off) ? sc[t - off] : 0;
        __syncthreads();
        sc[t] += add;
        __syncthreads();
    }
    if (t < SCAN_B) boff[t] = sc[t] - v;       // exclusive
    if (t == SCAN_B - 1) row_ptr[N] = sc[t];   // total = TE
}

__global__ __launch_bounds__(256) void k_scan3(const int* __restrict__ deg,
                                               const int* __restrict__ boff,
                                               int* __restrict__ row_ptr) {
    __shared__ int sc[256];
    int t = threadIdx.x;
    int v = blockIdx.x * 256 + t;
    int d = (v < N) ? deg[v] : 0;
    sc[t] = d;
    __syncthreads();
    #pragma unroll
    for (int off = 1; off < 256; off <<= 1) {
        int add = (t >= off) ? sc[t - off] : 0;
        __syncthreads();
        sc[t] += add;
        __syncthreads();
    }
    if (v < N) row_ptr[v] = boff[blockIdx.x] + sc[t] - d;
}

// ---------- fill: only src_csr (dst implied by CSR row) ----------
__global__ __launch_bounds__(256) void k_fill(const int* __restrict__ ei,
                                              const int* __restrict__ row_ptr,
                                              int* __restrict__ fill,
                                              int* __restrict__ src_csr) {
    int e = blockIdx.x * 256 + threadIdx.x;
    if (e >= TE) return;
    int s, d; edge_sd(e, ei, s, d);
    int pos = atomicAdd(fill + d, 1);
    src_csr[row_ptr[d] + pos] = s;
}

// ---------- per-edge softmax numerator + denominator, 16-lane group per dst node ----------
__global__ __launch_bounds__(256) void k_edge_soft(const int* __restrict__ row_ptr,
                                                   const int* __restrict__ src_csr,
                                                   const float* __restrict__ ai,
                                                   const float* __restrict__ aj,
                                                   float* __restrict__ alpha,
                                                   float* __restrict__ den) {
    int g = threadIdx.x >> 4, l16 = threadIdx.x & 15;
    int v = blockIdx.x * 16 + g;
    if (v >= N) return;
    int beg = row_ptr[v], end = row_ptr[v + 1];
    float aiv = ai[v];                       // dst-side dot, group-uniform
    for (int idx = beg + l16; idx < end; idx += 16) {
        int s = src_csr[idx];
        float a  = lrelu(aiv + aj[s], 0.2f);
        float ex = expf(a);
        alpha[idx] = ex;
        atomicAdd(den + s, ex);
    }
}

// ---------- per-node reciprocal of denominator ----------
__global__ __launch_bounds__(256) void k_invden(const float* __restrict__ den,
                                                float* __restrict__ invden) {
    int v = blockIdx.x * 256 + threadIdx.x;
    if (v >= N) return;
    invden[v] = 1.0f / (den[v] + 1e-16f);
}

// ---------- aggregation: wave per dst node, pair-gather (2 edges/instruction) ----------
// Half-wave h processes edges idx+2t+h; each lane reads uint2 (4 bf16, 8 B) of the
// H row -> 32 lanes cover the 256 B row, 2 rows in flight per issued gather.
// Cross-half shfl_xor(32) reduce + float4 store. (R9 NOTE: no per-slot clamping in
// the hot loop — predication before gathers kills MLP.)
__global__ __launch_bounds__(256) void k_aggregate(const int* __restrict__ row_ptr,
                                                   const int* __restrict__ src_csr,
                                                   const float* __restrict__ alpha,
                                                   const float* __restrict__ invden,
                                                   const uint2* __restrict__ Hu2, // 4 bf16 per uint2
                                                   const float* __restrict__ bvec,
                                                   float* __restrict__ O) {
    int wid = threadIdx.x >> 6, lane = threadIdx.x & 63;
    int h = lane >> 5, l32 = lane & 31;
    int v = blockIdx.x * 4 + wid;
    if (v >= N) return;
    int beg = row_ptr[v], end = row_ptr[v + 1];   // non-empty (self loop)
    float a0 = 0.f, a1 = 0.f, a2 = 0.f, a3 = 0.f;
    int idx = beg;
    for (; idx + 8 <= end; idx += 8) {            // 4 pairs = 8 edges
        int   s[4];
        float w[4];
        uint2 u[4];
        #pragma unroll
        for (int t = 0; t < 4; t++) s[t] = src_csr[idx + 2 * t + h];
        #pragma unroll
        for (int t = 0; t < 4; t++) w[t] = alpha[idx + 2 * t + h] * invden[s[t]];
        #pragma unroll
        for (int t = 0; t < 4; t++) u[t] = Hu2[(size_t)s[t] * 32 + l32];
        #pragma unroll
        for (int t = 0; t < 4; t++) {
            a0 += w[t] * __uint_as_float(u[t].x << 16);
            a1 += w[t] * __uint_as_float(u[t].x & 0xFFFF0000u);
            a2 += w[t] * __uint_as_float(u[t].y << 16);
            a3 += w[t] * __uint_as_float(u[t].y & 0xFFFF0000u);
        }
    }
    for (; idx + 2 <= end; idx += 2) {            // pair tail
        int s = src_csr[idx + h];
        float w = alpha[idx + h] * invden[s];
        uint2 u = Hu2[(size_t)s * 32 + l32];
        a0 += w * __uint_as_float(u.x << 16);
        a1 += w * __uint_as_float(u.x & 0xFFFF0000u);
        a2 += w * __uint_as_float(u.y << 16);
        a3 += w * __uint_as_float(u.y & 0xFFFF0000u);
    }
    if (idx < end) {                              // single tail: half 1 weight 0
        int s = src_csr[idx];
        float w = (h == 0) ? alpha[idx] * invden[s] : 0.f;
        uint2 u = Hu2[(size_t)s * 32 + l32];
        a0 += w * __uint_as_float(u.x << 16);
        a1 += w * __uint_as_float(u.x & 0xFFFF0000u);
        a2 += w * __uint_as_float(u.y << 16);
        a3 += w * __uint_as_float(u.y & 0xFFFF0000u);
    }
    a0 += __shfl_xor(a0, 32);
    a1 += __shfl_xor(a1, 32);
    a2 += __shfl_xor(a2, 32);
    a3 += __shfl_xor(a3, 32);
    if (h == 0) {
        float4 b = ((const float4*)bvec)[l32];
        float4 o;
        o.x = fmaxf(a0 + b.x, 0.f);
        o.y = fmaxf(a1 + b.y, 0.f);
        o.z = fmaxf(a2 + b.z, 0.f);
        o.w = fmaxf(a3 + b.w, 0.f);
        *(float4*)(O + (size_t)v * D + l32 * 4) = o;
    }
}

// ---------- BN column stats: float4 per thread, 8 row-groups, LDS reduce, no fences ----------
// NOTE (R11): last-block finalize via __threadfence() cost ~35 us/layer on gfx950
// (device-scope fence = per-XCD L2 writeback per block). Keep bnfinal as its own launch.
__global__ __launch_bounds__(256) void k_stats(const float* __restrict__ O,
                                               float* __restrict__ colsum, float* __restrict__ colsq) {
    int c4 = (threadIdx.x & 31) * 4;   // column base (4 cols per thread)
    int rg = threadIdx.x >> 5;         // row group 0..7
    float s0=0.f,s1=0.f,s2=0.f,s3=0.f,q0=0.f,q1=0.f,q2=0.f,q3=0.f;
    for (int v = blockIdx.x * 8 + rg; v < N; v += gridDim.x * 8) {
        float4 val = *(const float4*)(O + (size_t)v * D + c4);
        s0 += val.x; q0 += val.x * val.x;
        s1 += val.y; q1 += val.y * val.y;
        s2 += val.z; q2 += val.z * val.z;
        s3 += val.w; q3 += val.w * val.w;
    }
    __shared__ float ls[8][128], lq[8][128];   // 8 KB
    ls[rg][c4+0]=s0; ls[rg][c4+1]=s1; ls[rg][c4+2]=s2; ls[rg][c4+3]=s3;
    lq[rg][c4+0]=q0; lq[rg][c4+1]=q1; lq[rg][c4+2]=q2; lq[rg][c4+3]=q3;
    __syncthreads();
    if (threadIdx.x < 128) {
        int c = threadIdx.x;
        float s = 0.f, q = 0.f;
        #pragma unroll
        for (int r = 0; r < 8; r++) { s += ls[r][c]; q += lq[r][c]; }
        atomicAdd(colsum + c, s);
        atomicAdd(colsq + c, q);
    }
}

__global__ __launch_bounds__(128) void k_bnfinal(const float* __restrict__ colsum,
                                                 const float* __restrict__ colsq,
                                                 const float* __restrict__ g,
                                                 const float* __restrict__ be,
                                                 float* __restrict__ ss) {
    int c = threadIdx.x;
    float mean = colsum[c] / (float)N;
    float var  = colsq[c] / (float)N - mean * mean;
    float scale = g[c] * rsqrtf(var + 1e-5f);
    ss[c] = scale;
    ss[128 + c] = be[c] - mean * scale;
}

// ---------- decoder ----------
__global__ __launch_bounds__(256) void k_T(const float* __restrict__ P1, const float* __restrict__ P2,
                                           float* __restrict__ T) {
    int t = blockIdx.x * 256 + threadIdx.x;
    if (t >= 128 * 64) return;
    int i = t >> 6, d = t & 63;
    float s = 0.f;
    #pragma unroll 8
    for (int k = 0; k < 64; k++) s += P1[i * 64 + k] * P2[k * 64 + d];
    T[t] = s;
}

__global__ __launch_bounds__(256) void k_M(const float* __restrict__ T, const float* __restrict__ P1,
                                           float* __restrict__ M) {
    int t = blockIdx.x * 256 + threadIdx.x;
    if (t >= 128 * 128) return;
    int i = t >> 7, j = t & 127;
    float s = 0.f;
    #pragma unroll 8
    for (int d = 0; d < 64; d++) s += T[i * 64 + d] * P1[j * 64 + d];
    M[t] = s;
}

__global__ __launch_bounds__(128) void k_pred(const float* __restrict__ O,
                                              const float* __restrict__ ss,
                                              const int* __restrict__ drug,
                                              const float* __restrict__ M,
                                              float* __restrict__ out) {
    int b = blockIdx.x, i = threadIdx.x;
    __shared__ float av[128], bv[128];
    int ia = drug[b * 2] - 1, ib = drug[b * 2 + 1] - 1;
    float sc = ss[i], sh = ss[128 + i];
    av[i] = lrelu(O[(size_t)ia * D + i] * sc + sh, 0.1f);
    bv[i] = lrelu(O[(size_t)ib * D + i] * sc + sh, 0.1f);
    __syncthreads();
    float u = 0.f;
    #pragma unroll 8
    for (int j = 0; j < 128; j++) u += M[i * 128 + j] * bv[j];
    float val = av[i] * u;
    #pragma unroll
    for (int off = 32; off; off >>= 1) val += __shfl_down(val, off);
    __shared__ float red[2];
    if ((i & 63) == 0) red[i >> 6] = val;
    __syncthreads();
    if (i == 0) out[b] = red[0] + red[1];
}

extern "C" void kernel_launch(void* const* d_in, const int* in_sizes, int n_in,
                              void* d_out, int out_size, void* d_ws, size_t ws_size,
                              hipStream_t stream) {
    const float* x    = (const float*)d_in[0];
    const int*   ei   = (const int*)  d_in[1];
    const int*   drug = (const int*)  d_in[2];
    const float* W[3]   = {(const float*)d_in[3], (const float*)d_in[8],  (const float*)d_in[13]};
    const float* att[3] = {(const float*)d_in[4], (const float*)d_in[9],  (const float*)d_in[14]};
    const float* bb[3]  = {(const float*)d_in[5], (const float*)d_in[10], (const float*)d_in[15]};
    const float* gg[3]  = {(const float*)d_in[6], (const float*)d_in[11], (const float*)d_in[16]};
    const float* be[3]  = {(const float*)d_in[7], (const float*)d_in[12], (const float*)d_in[17]};
    const float* P1 = (const float*)d_in[18];
    const float* P2 = (const float*)d_in[19];

    float* ws = (float*)d_ws;
    size_t o_H      = 0;                     // bf16 H: N*D ushorts = N*64 floats
    size_t o_O      = o_H + (size_t)N * 64;
    size_t o_ai     = o_O + (size_t)N * D;
    size_t o_aj     = o_ai + N;
    size_t o_den    = o_aj + N;        // [den | colsum | colsq]: one memset per layer
    size_t o_colsum = o_den + N;       // 128
    size_t o_colsq  = o_colsum + 128;  // 128
    size_t o_inv    = o_colsq + 128;
    size_t o_alpha  = o_inv + N;
    size_t o_deg    = o_alpha + TE;    // [deg | fill]: one memset in CSR build
    size_t o_fill   = o_deg + N;       // int
    size_t o_rowptr = o_fill + N;      // int, N+1 (pad 8)
    size_t o_src    = o_rowptr + N + 8;// int, TE
    size_t o_bsum   = o_src + TE;      // int, SCAN_B (pad to 256)
    size_t o_boff   = o_bsum + 256;    // int, SCAN_B (pad to 256)
    size_t o_ss     = o_boff + 256;    // 256
    size_t o_T      = o_ss + 256;      // 128*64
    size_t o_Mm     = o_T + 128 * 64;  // 128*128
    size_t o_Wb     = o_Mm + 128 * 128;// 3*16384 ushorts = 24576 floats

    unsigned short* Hb16 = (unsigned short*)(ws + o_H);
    uint2*          Hu2  = (uint2*)(ws + o_H);
    float*    Ob    = ws + o_O;
    float*    ai    = ws + o_ai;
    float*    aj    = ws + o_aj;
    float*    den   = ws + o_den;
    float*    csum  = ws + o_colsum;
    float*    csq   = ws + o_colsq;
    float*    inv   = ws + o_inv;
    float*    alpha = ws + o_alpha;
    int*      deg   = (int*)(ws + o_deg);
    int*      fill  = (int*)(ws + o_fill);
    int*      rowp  = (int*)(ws + o_rowptr);
    int*      srcc  = (int*)(ws + o_src);
    int*      bsum  = (int*)(ws + o_bsum);
    int*      boff  = (int*)(ws + o_boff);
    float*    ss    = ws + o_ss;
    float*    Tm    = ws + o_T;
    float*    Mm    = ws + o_Mm;
    unsigned short* Wb = (unsigned short*)(ws + o_Wb);

    const int EB = (TE + 255) / 256;
    const int NB4  = (N + 3) / 4;
    const int NB16 = (N + 15) / 16;

    // ---- CSR by dst ----
    hipMemsetAsync(deg, 0, (size_t)2 * N * 4, stream);   // deg + fill
    k_deg<<<EB, 256, 0, stream>>>(ei, deg);
    k_scan1<<<SCAN_B, 256, 0, stream>>>(deg, bsum);
    k_scan2<<<1, 256, 0, stream>>>(bsum, boff, rowp);
    k_scan3<<<SCAN_B, 256, 0, stream>>>(deg, boff, rowp);
    k_fill<<<EB, 256, 0, stream>>>(ei, rowp, fill, srcc);

    // ---- W bf16 copies (one launch) ----
    k_wb3<<<192, 256, 0, stream>>>(W[0], W[1], W[2], Wb);

    // ---- 3 GAT layers ----
    for (int l = 0; l < 3; l++) {
        const float* Xin = (l == 0) ? x : Ob;
        hipMemsetAsync(den, 0, (size_t)(N + 256) * 4, stream);  // den + colsum + colsq
        k_gemm<<<GEMM_B, 256, 0, stream>>>(Xin, Wb + l * 16384, Hb16, att[l], ai, aj, ss, l > 0 ? 1 : 0);
        k_edge_soft<<<NB16, 256, 0, stream>>>(rowp, srcc, ai, aj, alpha, den);
        k_invden<<<SCAN_B, 256, 0, stream>>>(den, inv);
        k_aggregate<<<NB4, 256, 0, stream>>>(rowp, srcc, alpha, inv, Hu2, bb[l], Ob);
        k_stats<<<256, 256, 0, stream>>>(Ob, csum, csq);
        k_bnfinal<<<1, 128, 0, stream>>>(csum, csq, gg[l], be[l], ss);
    }

    // ---- decoder ----
    k_T<<<32, 256, 0, stream>>>(P1, P2, Tm);
    k_M<<<64, 256, 0, stream>>>(Tm, P1, Mm);
    k_pred<<<1024, 128, 0, stream>>>(Ob, ss, drug, Mm, (float*)d_out);
}

// Round 14
// 532.414 us; speedup vs baseline: 1.1961x; 1.0002x over previous
//
#include <hip/hip_runtime.h>
#include <hip/hip_bf16.h>

#define DEVINL __device__ __forceinline__

constexpr int N  = 50000;
constexpr int E  = 600000;
constexpr int TE = E + N;      // edges + self loops
constexpr int D  = 128;
constexpr int SCAN_B = (N + 255) / 256;   // 196 blocks for hierarchical scan
constexpr int GEMM_ROWS = 64;             // 16 rows per wave, 4 waves
constexpr int GEMM_B = (N + GEMM_ROWS - 1) / GEMM_ROWS;  // 782
constexpr int HST_STRIDE = 136;           // ushorts; 272 B row: 16B-aligned, quad-staggered banks

typedef short bf16x8 __attribute__((ext_vector_type(8)));
typedef float f32x4  __attribute__((ext_vector_type(4)));

DEVINL float lrelu(float x, float s) { return x >= 0.f ? x : s * x; }

DEVINL unsigned short f2bf(float f) {   // RNE fp32 -> bf16
    unsigned u = __float_as_uint(f);
    u += 0x7FFFu + ((u >> 16) & 1u);
    return (unsigned short)(u >> 16);
}

// ---------- W -> bf16 copy for all 3 layers (layout unchanged: Wb[o][k]) ----------
__global__ __launch_bounds__(256) void k_wb3(const float* __restrict__ W0,
                                             const float* __restrict__ W1,
                                             const float* __restrict__ W2,
                                             unsigned short* __restrict__ Wb) {
    int b = blockIdx.x;          // 192 blocks: 64 per layer
    int l = b >> 6;
    const float* W = (l == 0) ? W0 : (l == 1) ? W1 : W2;
    int t = (b & 63) * 256 + threadIdx.x;   // 0..16383
    Wb[l * 16384 + t] = f2bf(W[t]);
}

// ---------- MFMA GEMM: H[v,o] = sum_k Xbn[v,k] * W[o,k]  (bf16 inputs, fp32 acc) ----------
// Epilogue: per-wave LDS transpose staging -> coalesced dwordx4 H stores
// (direct per-lane ushort stores were 32 ops x 4 rows x 32B chunks per wave).
__global__ __launch_bounds__(256) void k_gemm(const float* __restrict__ X,
                                              const unsigned short* __restrict__ Wb,
                                              unsigned short* __restrict__ Hb16,
                                              const float* __restrict__ att,
                                              float* __restrict__ ai,
                                              float* __restrict__ aj,
                                              const float* __restrict__ ss, // scale[128], shift[128]
                                              int apply_bn) {
    __shared__ unsigned short hst[4][16][HST_STRIDE];   // ~17 KB
    int wave = threadIdx.x >> 6, lane = threadIdx.x & 63;
    int m = lane & 15, quad = lane >> 4;
    int r0 = blockIdx.x * GEMM_ROWS + wave * 16;

    // ---- A fragments for 4 K-steps ----
    bf16x8 afrag[4];
    int rowA = r0 + m;
    bool rowok = rowA < N;
    #pragma unroll
    for (int k4 = 0; k4 < 4; k4++) {
        int c0 = k4 * 32 + quad * 8;   // feature column of first element
        float v[8];
        if (rowok) {
            float4 x0 = *(const float4*)(X + (size_t)rowA * D + c0);
            float4 x1 = *(const float4*)(X + (size_t)rowA * D + c0 + 4);
            v[0] = x0.x; v[1] = x0.y; v[2] = x0.z; v[3] = x0.w;
            v[4] = x1.x; v[5] = x1.y; v[6] = x1.z; v[7] = x1.w;
            if (apply_bn) {
                #pragma unroll
                for (int j = 0; j < 8; j++)
                    v[j] = lrelu(v[j] * ss[c0 + j] + ss[128 + c0 + j], 0.1f);
            }
        } else {
            #pragma unroll
            for (int j = 0; j < 8; j++) v[j] = 0.f;
        }
        #pragma unroll
        for (int j = 0; j < 8; j++) afrag[k4][j] = (short)f2bf(v[j]);
    }

    // ---- 8 col-tiles of 16, K=128 via 4 MFMA each ----
    float pii[4] = {0.f, 0.f, 0.f, 0.f};
    float pjj[4] = {0.f, 0.f, 0.f, 0.f};
    #pragma unroll
    for (int nt = 0; nt < 8; nt++) {
        int n0 = nt * 16;
        f32x4 acc = {0.f, 0.f, 0.f, 0.f};
        const unsigned short* wrow = Wb + (size_t)(n0 + m) * D + quad * 8;
        #pragma unroll
        for (int k4 = 0; k4 < 4; k4++) {
            bf16x8 b = *(const bf16x8*)(wrow + k4 * 32);
            acc = __builtin_amdgcn_mfma_f32_16x16x32_bf16(afrag[k4], b, acc, 0, 0, 0);
        }
        float ad = att[n0 + m];
        float as = att[128 + n0 + m];
        #pragma unroll
        for (int i = 0; i < 4; i++) {
            hst[wave][quad * 4 + i][n0 + m] = f2bf(acc[i]);
            pii[i] += acc[i] * ad;
            pjj[i] += acc[i] * as;
        }
    }

    // ---- coalesced H flush: lane reads 16B of a staged row, dwordx4 store ----
    #pragma unroll
    for (int t = 0; t < 4; t++) {
        int r = t * 4 + quad;              // 0..15 within wave tile
        int row = r0 + r;
        int cb = m * 8;                    // ushort col base (16 B)
        uint4 vv = *(const uint4*)&hst[wave][r][cb];
        if (row < N)
            *(uint4*)(Hb16 + (size_t)row * D + cb) = vv;
    }

    // ---- reduce attention dots across the 16 lanes of each quad ----
    #pragma unroll
    for (int mask = 8; mask >= 1; mask >>= 1) {
        #pragma unroll
        for (int i = 0; i < 4; i++) {
            pii[i] += __shfl_xor(pii[i], mask);
            pjj[i] += __shfl_xor(pjj[i], mask);
        }
    }
    if (m == 0) {
        #pragma unroll
        for (int i = 0; i < 4; i++) {
            int row = r0 + quad * 4 + i;
            if (row < N) { ai[row] = pii[i]; aj[row] = pjj[i]; }
        }
    }
}

DEVINL void edge_sd(int e, const int* ei, int& s, int& d) {
    if (e < E) { s = ei[e]; d = ei[E + e]; }
    else       { s = d = e - E; }
}

// ---------- CSR build by dst (once; graph shared across layers) ----------
__global__ __launch_bounds__(256) void k_deg(const int* __restrict__ ei, int* __restrict__ deg) {
    int e = blockIdx.x * 256 + threadIdx.x;
    if (e >= TE) return;
    int s, d; edge_sd(e, ei, s, d);
    atomicAdd(deg + d, 1);
}

__global__ __launch_bounds__(256) void k_scan1(const int* __restrict__ deg, int* __restrict__ bsum) {
    __shared__ int red[256];
    int t = threadIdx.x;
    int v = blockIdx.x * 256 + t;
    red[t] = (v < N) ? deg[v] : 0;
    __syncthreads();
    #pragma unroll
    for (int off = 128; off; off >>= 1) {
        if (t < off) red[t] += red[t + off];
        __syncthreads();
    }
    if (t == 0) bsum[blockIdx.x] = red[0];
}

__global__ __launch_bounds__(256) void k_scan2(const int* __restrict__ bsum,
                                               int* __restrict__ boff, int* __restrict__ row_ptr) {
    __shared__ int sc[256];
    int t = threadIdx.x;
    int v = (t < SCAN_B) ? bsum[t] : 0;
    sc[t] = v;
    __syncthreads();
    #pragma unroll
    for (int off = 1; off < 256; off <<= 1) {
        int add = (t >= off) ? sc[t - off] : 0;
        __syncthreads();
        sc[t] += add;
        __syncthreads();
    }
    if (t < SCAN_B) boff[t] = sc[t] - v;       // exclusive
    if (t == SCAN_B - 1) row_ptr[N] = sc[t];   // total = TE
}

__global__ __launch_bounds__(256) void k_scan3(const int* __restrict__ deg,
                                               const int* __restrict__ boff,
                                               int* __restrict__ row_ptr) {
    __shared__ int sc[256];
    int t = threadIdx.x;
    int v = blockIdx.x * 256 + t;
    int d = (v < N) ? deg[v] : 0;
    sc[t] = d;
    __syncthreads();
    #pragma unroll
    for (int off = 1; off < 256; off <<= 1) {
        int add = (t >= off) ? sc[t - off] : 0;
        __syncthreads();
        sc[t] += add;
        __syncthreads();
    }
    if (v < N) row_ptr[v] = boff[blockIdx.x] + sc[t] - d;
}

// ---------- fill: only src_csr (dst implied by CSR row) ----------
__global__ __launch_bounds__(256) void k_fill(const int* __restrict__ ei,
                                              const int* __restrict__ row_ptr,
                                              int* __restrict__ fill,
                                              int* __restrict__ src_csr) {
    int e = blockIdx.x * 256 + threadIdx.x;
    if (e >= TE) return;
    int s, d; edge_sd(e, ei, s, d);
    int pos = atomicAdd(fill + d, 1);
    src_csr[row_ptr[d] + pos] = s;
}

// ---------- per-edge softmax numerator + denominator, 16-lane group per dst node ----------
__global__ __launch_bounds__(256) void k_edge_soft(const int* __restrict__ row_ptr,
                                                   const int* __restrict__ src_csr,
                                                   const float* __restrict__ ai,
                                                   const float* __restrict__ aj,
                                                   float* __restrict__ alpha,
                                                   float* __restrict__ den) {
    int g = threadIdx.x >> 4, l16 = threadIdx.x & 15;
    int v = blockIdx.x * 16 + g;
    if (v >= N) return;
    int beg = row_ptr[v], end = row_ptr[v + 1];
    float aiv = ai[v];                       // dst-side dot, group-uniform
    for (int idx = beg + l16; idx < end; idx += 16) {
        int s = src_csr[idx];
        float a  = lrelu(aiv + aj[s], 0.2f);
        float ex = expf(a);
        alpha[idx] = ex;
        atomicAdd(den + s, ex);
    }
}

// ---------- per-node reciprocal of denominator ----------
__global__ __launch_bounds__(256) void k_invden(const float* __restrict__ den,
                                                float* __restrict__ invden) {
    int v = blockIdx.x * 256 + threadIdx.x;
    if (v >= N) return;
    invden[v] = 1.0f / (den[v] + 1e-16f);
}

// ---------- aggregation: wave per dst node, pair-gather (2 edges/instruction) ----------
// (R9 NOTE: no per-slot clamping in the hot loop — predication before gathers kills MLP.)
__global__ __launch_bounds__(256) void k_aggregate(const int* __restrict__ row_ptr,
                                                   const int* __restrict__ src_csr,
                                                   const float* __restrict__ alpha,
                                                   const float* __restrict__ invden,
                                                   const uint2* __restrict__ Hu2, // 4 bf16 per uint2
                                                   const float* __restrict__ bvec,
                                                   float* __restrict__ O) {
    int wid = threadIdx.x >> 6, lane = threadIdx.x & 63;
    int h = lane >> 5, l32 = lane & 31;
    int v = blockIdx.x * 4 + wid;
    if (v >= N) return;
    int beg = row_ptr[v], end = row_ptr[v + 1];   // non-empty (self loop)
    float a0 = 0.f, a1 = 0.f, a2 = 0.f, a3 = 0.f;
    int idx = beg;
    for (; idx + 8 <= end; idx += 8) {            // 4 pairs = 8 edges
        int   s[4];
        float w[4];
        uint2 u[4];
        #pragma unroll
        for (int t = 0; t < 4; t++) s[t] = src_csr[idx + 2 * t + h];
        #pragma unroll
        for (int t = 0; t < 4; t++) w[t] = alpha[idx + 2 * t + h] * invden[s[t]];
        #pragma unroll
        for (int t = 0; t < 4; t++) u[t] = Hu2[(size_t)s[t] * 32 + l32];
        #pragma unroll
        for (int t = 0; t < 4; t++) {
            a0 += w[t] * __uint_as_float(u[t].x << 16);
            a1 += w[t] * __uint_as_float(u[t].x & 0xFFFF0000u);
            a2 += w[t] * __uint_as_float(u[t].y << 16);
            a3 += w[t] * __uint_as_float(u[t].y & 0xFFFF0000u);
        }
    }
    for (; idx + 2 <= end; idx += 2) {            // pair tail
        int s = src_csr[idx + h];
        float w = alpha[idx + h] * invden[s];
        uint2 u = Hu2[(size_t)s * 32 + l32];
        a0 += w * __uint_as_float(u.x << 16);
        a1 += w * __uint_as_float(u.x & 0xFFFF0000u);
        a2 += w * __uint_as_float(u.y << 16);
        a3 += w * __uint_as_float(u.y & 0xFFFF0000u);
    }
    if (idx < end) {                              // single tail: half 1 weight 0
        int s = src_csr[idx];
        float w = (h == 0) ? alpha[idx] * invden[s] : 0.f;
        uint2 u = Hu2[(size_t)s * 32 + l32];
        a0 += w * __uint_as_float(u.x << 16);
        a1 += w * __uint_as_float(u.x & 0xFFFF0000u);
        a2 += w * __uint_as_float(u.y << 16);
        a3 += w * __uint_as_float(u.y & 0xFFFF0000u);
    }
    a0 += __shfl_xor(a0, 32);
    a1 += __shfl_xor(a1, 32);
    a2 += __shfl_xor(a2, 32);
    a3 += __shfl_xor(a3, 32);
    if (h == 0) {
        float4 b = ((const float4*)bvec)[l32];
        float4 o;
        o.x = fmaxf(a0 + b.x, 0.f);
        o.y = fmaxf(a1 + b.y, 0.f);
        o.z = fmaxf(a2 + b.z, 0.f);
        o.w = fmaxf(a3 + b.w, 0.f);
        *(float4*)(O + (size_t)v * D + l32 * 4) = o;
    }
}

// ---------- BN column stats: float4 per thread, 8 row-groups, LDS reduce, no fences ----------
// NOTE (R11): last-block finalize via __threadfence() cost ~35 us/layer on gfx950
// (device-scope fence = per-XCD L2 writeback per block). Keep bnfinal as its own launch.
__global__ __launch_bounds__(256) void k_stats(const float* __restrict__ O,
                                               float* __restrict__ colsum, float* __restrict__ colsq) {
    int c4 = (threadIdx.x & 31) * 4;   // column base (4 cols per thread)
    int rg = threadIdx.x >> 5;         // row group 0..7
    float s0=0.f,s1=0.f,s2=0.f,s3=0.f,q0=0.f,q1=0.f,q2=0.f,q3=0.f;
    for (int v = blockIdx.x * 8 + rg; v < N; v += gridDim.x * 8) {
        float4 val = *(const float4*)(O + (size_t)v * D + c4);
        s0 += val.x; q0 += val.x * val.x;
        s1 += val.y; q1 += val.y * val.y;
        s2 += val.z; q2 += val.z * val.z;
        s3 += val.w; q3 += val.w * val.w;
    }
    __shared__ float ls[8][128], lq[8][128];   // 8 KB
    ls[rg][c4+0]=s0; ls[rg][c4+1]=s1; ls[rg][c4+2]=s2; ls[rg][c4+3]=s3;
    lq[rg][c4+0]=q0; lq[rg][c4+1]=q1; lq[rg][c4+2]=q2; lq[rg][c4+3]=q3;
    __syncthreads();
    if (threadIdx.x < 128) {
        int c = threadIdx.x;
        float s = 0.f, q = 0.f;
        #pragma unroll
        for (int r = 0; r < 8; r++) { s += ls[r][c]; q += lq[r][c]; }
        atomicAdd(colsum + c, s);
        atomicAdd(colsq + c, q);
    }
}

__global__ __launch_bounds__(128) void k_bnfinal(const float* __restrict__ colsum,
                                                 const float* __restrict__ colsq,
                                                 const float* __restrict__ g,
                                                 const float* __restrict__ be,
                                                 float* __restrict__ ss) {
    int c = threadIdx.x;
    float mean = colsum[c] / (float)N;
    float var  = colsq[c] / (float)N - mean * mean;
    float scale = g[c] * rsqrtf(var + 1e-5f);
    ss[c] = scale;
    ss[128 + c] = be[c] - mean * scale;
}

// ---------- decoder ----------
__global__ __launch_bounds__(256) void k_T(const float* __restrict__ P1, const float* __restrict__ P2,
                                           float* __restrict__ T) {
    int t = blockIdx.x * 256 + threadIdx.x;
    if (t >= 128 * 64) return;
    int i = t >> 6, d = t & 63;
    float s = 0.f;
    #pragma unroll 8
    for (int k = 0; k < 64; k++) s += P1[i * 64 + k] * P2[k * 64 + d];
    T[t] = s;
}

__global__ __launch_bounds__(256) void k_M(const float* __restrict__ T, const float* __restrict__ P1,
                                           float* __restrict__ M) {
    int t = blockIdx.x * 256 + threadIdx.x;
    if (t >= 128 * 128) return;
    int i = t >> 7, j = t & 127;
    float s = 0.f;
    #pragma unroll 8
    for (int d = 0; d < 64; d++) s += T[i * 64 + d] * P1[j * 64 + d];
    M[t] = s;
}

__global__ __launch_bounds__(128) void k_pred(const float* __restrict__ O,
                                              const float* __restrict__ ss,
                                              const int* __restrict__ drug,
                                              const float* __restrict__ M,
                                              float* __restrict__ out) {
    int b = blockIdx.x, i = threadIdx.x;
    __shared__ float av[128], bv[128];
    int ia = drug[b * 2] - 1, ib = drug[b * 2 + 1] - 1;
    float sc = ss[i], sh = ss[128 + i];
    av[i] = lrelu(O[(size_t)ia * D + i] * sc + sh, 0.1f);
    bv[i] = lrelu(O[(size_t)ib * D + i] * sc + sh, 0.1f);
    __syncthreads();
    const float4* M4  = (const float4*)(M + (size_t)i * 128);
    const float4* bv4 = (const float4*)bv;
    float u = 0.f;
    #pragma unroll 8
    for (int j = 0; j < 32; j++) {
        float4 mv = M4[j];
        float4 bb = bv4[j];
        u += mv.x * bb.x + mv.y * bb.y + mv.z * bb.z + mv.w * bb.w;
    }
    float val = av[i] * u;
    #pragma unroll
    for (int off = 32; off; off >>= 1) val += __shfl_down(val, off);
    __shared__ float red[2];
    if ((i & 63) == 0) red[i >> 6] = val;
    __syncthreads();
    if (i == 0) out[b] = red[0] + red[1];
}

extern "C" void kernel_launch(void* const* d_in, const int* in_sizes, int n_in,
                              void* d_out, int out_size, void* d_ws, size_t ws_size,
                              hipStream_t stream) {
    const float* x    = (const float*)d_in[0];
    const int*   ei   = (const int*)  d_in[1];
    const int*   drug = (const int*)  d_in[2];
    const float* W[3]   = {(const float*)d_in[3], (const float*)d_in[8],  (const float*)d_in[13]};
    const float* att[3] = {(const float*)d_in[4], (const float*)d_in[9],  (const float*)d_in[14]};
    const float* bb[3]  = {(const float*)d_in[5], (const float*)d_in[10], (const float*)d_in[15]};
    const float* gg[3]  = {(const float*)d_in[6], (const float*)d_in[11], (const float*)d_in[16]};
    const float* be[3]  = {(const float*)d_in[7], (const float*)d_in[12], (const float*)d_in[17]};
    const float* P1 = (const float*)d_in[18];
    const float* P2 = (const float*)d_in[19];

    float* ws = (float*)d_ws;
    size_t o_H      = 0;                     // bf16 H: N*D ushorts = N*64 floats
    size_t o_O      = o_H + (size_t)N * 64;
    size_t o_ai     = o_O + (size_t)N * D;
    size_t o_aj     = o_ai + N;
    size_t o_den    = o_aj + N;        // [den | colsum | colsq]: one memset per layer
    size_t o_colsum = o_den + N;       // 128
    size_t o_colsq  = o_colsum + 128;  // 128
    size_t o_inv    = o_colsq + 128;
    size_t o_alpha  = o_inv + N;
    size_t o_deg    = o_alpha + TE;    // [deg | fill]: one memset in CSR build
    size_t o_fill   = o_deg + N;       // int
    size_t o_rowptr = o_fill + N;      // int, N+1 (pad 8)
    size_t o_src    = o_rowptr + N + 8;// int, TE
    size_t o_bsum   = o_src + TE;      // int, SCAN_B (pad to 256)
    size_t o_boff   = o_bsum + 256;    // int, SCAN_B (pad to 256)
    size_t o_ss     = o_boff + 256;    // 256
    size_t o_T      = o_ss + 256;      // 128*64
    size_t o_Mm     = o_T + 128 * 64;  // 128*128
    size_t o_Wb     = o_Mm + 128 * 128;// 3*16384 ushorts = 24576 floats

    unsigned short* Hb16 = (unsigned short*)(ws + o_H);
    uint2*          Hu2  = (uint2*)(ws + o_H);
    float*    Ob    = ws + o_O;
    float*    ai    = ws + o_ai;
    float*    aj    = ws + o_aj;
    float*    den   = ws + o_den;
    float*    csum  = ws + o_colsum;
    float*    csq   = ws + o_colsq;
    float*    inv   = ws + o_inv;
    float*    alpha = ws + o_alpha;
    int*      deg   = (int*)(ws + o_deg);
    int*      fill  = (int*)(ws + o_fill);
    int*      rowp  = (int*)(ws + o_rowptr);
    int*      srcc  = (int*)(ws + o_src);
    int*      bsum  = (int*)(ws + o_bsum);
    int*      boff  = (int*)(ws + o_boff);
    float*    ss    = ws + o_ss;
    float*    Tm    = ws + o_T;
    float*    Mm    = ws + o_Mm;
    unsigned short* Wb = (unsigned short*)(ws + o_Wb);

    const int EB = (TE + 255) / 256;
    const int NB4  = (N + 3) / 4;
    const int NB16 = (N + 15) / 16;

    // ---- CSR by dst ----
    hipMemsetAsync(deg, 0, (size_t)2 * N * 4, stream);   // deg + fill
    k_deg<<<EB, 256, 0, stream>>>(ei, deg);
    k_scan1<<<SCAN_B, 256, 0, stream>>>(deg, bsum);
    k_scan2<<<1, 256, 0, stream>>>(bsum, boff, rowp);
    k_scan3<<<SCAN_B, 256, 0, stream>>>(deg, boff, rowp);
    k_fill<<<EB, 256, 0, stream>>>(ei, rowp, fill, srcc);

    // ---- W bf16 copies (one launch) ----
    k_wb3<<<192, 256, 0, stream>>>(W[0], W[1], W[2], Wb);

    // ---- 3 GAT layers ----
    for (int l = 0; l < 3; l++) {
        const float* Xin = (l == 0) ? x : Ob;
        hipMemsetAsync(den, 0, (size_t)(N + 256) * 4, stream);  // den + colsum + colsq
        k_gemm<<<GEMM_B, 256, 0, stream>>>(Xin, Wb + l * 16384, Hb16, att[l], ai, aj, ss, l > 0 ? 1 : 0);
        k_edge_soft<<<NB16, 256, 0, stream>>>(rowp, srcc, ai, aj, alpha, den);
        k_invden<<<SCAN_B, 256, 0, stream>>>(den, inv);
        k_aggregate<<<NB4, 256, 0, stream>>>(rowp, srcc, alpha, inv, Hu2, bb[l], Ob);
        k_stats<<<256, 256, 0, stream>>>(Ob, csum, csq);
        k_bnfinal<<<1, 128, 0, stream>>>(csum, csq, gg[l], be[l], ss);
    }

    // ---- decoder ----
    k_T<<<32, 256, 0, stream>>>(P1, P2, Tm);
    k_M<<<64, 256, 0, stream>>>(Tm, P1, Mm);
    k_pred<<<1024, 128, 0, stream>>>(Ob, ss, drug, Mm, (float*)d_out);
}

// Round 15
// 524.037 us; speedup vs baseline: 1.2152x; 1.0160x over previous
//
#include <hip/hip_runtime.h>
#include <hip/hip_bf16.h>

#define DEVINL __device__ __forceinline__

constexpr int N  = 50000;
constexpr int E  = 600000;
constexpr int TE = E + N;      // edges + self loops
constexpr int D  = 128;
constexpr int SCAN_B = (N + 255) / 256;   // 196 blocks for hierarchical scan
constexpr int GEMM_ROWS = 64;             // 16 rows per wave, 4 waves
constexpr int GEMM_B = (N + GEMM_ROWS - 1) / GEMM_ROWS;  // 782
constexpr int HST_STRIDE = 136;           // ushorts; quad-staggered banks, 16B-aligned

typedef short bf16x8 __attribute__((ext_vector_type(8)));
typedef float f32x4  __attribute__((ext_vector_type(4)));

DEVINL float lrelu(float x, float s) { return x >= 0.f ? x : s * x; }

DEVINL unsigned short f2bf(float f) {   // RNE fp32 -> bf16
    unsigned u = __float_as_uint(f);
    u += 0x7FFFu + ((u >> 16) & 1u);
    return (unsigned short)(u >> 16);
}
DEVINL float bfl(unsigned u) { return __uint_as_float(u << 16); }          // low bf16
DEVINL float bfh(unsigned u) { return __uint_as_float(u & 0xFFFF0000u); }  // high bf16

// ---------- W -> bf16 copy for all 3 layers (layout unchanged: Wb[o][k]) ----------
__global__ __launch_bounds__(256) void k_wb3(const float* __restrict__ W0,
                                             const float* __restrict__ W1,
                                             const float* __restrict__ W2,
                                             unsigned short* __restrict__ Wb) {
    int b = blockIdx.x;          // 192 blocks: 64 per layer
    int l = b >> 6;
    const float* W = (l == 0) ? W0 : (l == 1) ? W1 : W2;
    int t = (b & 63) * 256 + threadIdx.x;   // 0..16383
    Wb[l * 16384 + t] = f2bf(W[t]);
}

// ---------- MFMA GEMM: H[v,o] = sum_k BN(Xin)[v,k] * W[o,k]  (bf16 in, fp32 acc) ----------
// apply_bn=0: input = fp32 X. apply_bn=1: input = bf16 O16; BN scale/shift computed
// per-block from colsum/colsq (replaces the separate k_bnfinal launch — R15).
__global__ __launch_bounds__(256) void k_gemm(const float* __restrict__ X,
                                              const unsigned short* __restrict__ O16,
                                              const unsigned short* __restrict__ Wb,
                                              unsigned short* __restrict__ Hb16,
                                              const float* __restrict__ att,
                                              float* __restrict__ ai,
                                              float* __restrict__ aj,
                                              const float* __restrict__ csum,
                                              const float* __restrict__ csq,
                                              const float* __restrict__ g,
                                              const float* __restrict__ be,
                                              int apply_bn) {
    __shared__ unsigned short hst[4][16][HST_STRIDE];   // ~17 KB
    __shared__ float ssl[256];                          // scale[128], shift[128]
    int wave = threadIdx.x >> 6, lane = threadIdx.x & 63;
    int m = lane & 15, quad = lane >> 4;
    int r0 = blockIdx.x * GEMM_ROWS + wave * 16;

    if (apply_bn) {
        if (threadIdx.x < 128) {
            int c = threadIdx.x;
            float mean = csum[c] / (float)N;
            float var  = csq[c] / (float)N - mean * mean;
            float scale = g[c] * rsqrtf(var + 1e-5f);
            ssl[c] = scale;
            ssl[128 + c] = be[c] - mean * scale;
        }
        __syncthreads();
    }

    // ---- A fragments for 4 K-steps ----
    bf16x8 afrag[4];
    int rowA = r0 + m;
    bool rowok = rowA < N;
    #pragma unroll
    for (int k4 = 0; k4 < 4; k4++) {
        int c0 = k4 * 32 + quad * 8;   // feature column of first element
        float v[8];
        if (rowok) {
            if (apply_bn) {
                uint4 hu = *(const uint4*)(O16 + (size_t)rowA * D + c0);
                v[0] = bfl(hu.x); v[1] = bfh(hu.x);
                v[2] = bfl(hu.y); v[3] = bfh(hu.y);
                v[4] = bfl(hu.z); v[5] = bfh(hu.z);
                v[6] = bfl(hu.w); v[7] = bfh(hu.w);
                #pragma unroll
                for (int j = 0; j < 8; j++)
                    v[j] = lrelu(v[j] * ssl[c0 + j] + ssl[128 + c0 + j], 0.1f);
            } else {
                float4 x0 = *(const float4*)(X + (size_t)rowA * D + c0);
                float4 x1 = *(const float4*)(X + (size_t)rowA * D + c0 + 4);
                v[0] = x0.x; v[1] = x0.y; v[2] = x0.z; v[3] = x0.w;
                v[4] = x1.x; v[5] = x1.y; v[6] = x1.z; v[7] = x1.w;
            }
        } else {
            #pragma unroll
            for (int j = 0; j < 8; j++) v[j] = 0.f;
        }
        #pragma unroll
        for (int j = 0; j < 8; j++) afrag[k4][j] = (short)f2bf(v[j]);
    }

    // ---- 8 col-tiles of 16, K=128 via 4 MFMA each ----
    float pii[4] = {0.f, 0.f, 0.f, 0.f};
    float pjj[4] = {0.f, 0.f, 0.f, 0.f};
    #pragma unroll
    for (int nt = 0; nt < 8; nt++) {
        int n0 = nt * 16;
        f32x4 acc = {0.f, 0.f, 0.f, 0.f};
        const unsigned short* wrow = Wb + (size_t)(n0 + m) * D + quad * 8;
        #pragma unroll
        for (int k4 = 0; k4 < 4; k4++) {
            bf16x8 b = *(const bf16x8*)(wrow + k4 * 32);
            acc = __builtin_amdgcn_mfma_f32_16x16x32_bf16(afrag[k4], b, acc, 0, 0, 0);
        }
        float ad = att[n0 + m];
        float as = att[128 + n0 + m];
        #pragma unroll
        for (int i = 0; i < 4; i++) {
            hst[wave][quad * 4 + i][n0 + m] = f2bf(acc[i]);
            pii[i] += acc[i] * ad;
            pjj[i] += acc[i] * as;
        }
    }

    // ---- coalesced H flush: lane reads 16B of a staged row, dwordx4 store ----
    #pragma unroll
    for (int t = 0; t < 4; t++) {
        int r = t * 4 + quad;              // 0..15 within wave tile
        int row = r0 + r;
        int cb = m * 8;                    // ushort col base (16 B)
        uint4 vv = *(const uint4*)&hst[wave][r][cb];
        if (row < N)
            *(uint4*)(Hb16 + (size_t)row * D + cb) = vv;
    }

    // ---- reduce attention dots across the 16 lanes of each quad ----
    #pragma unroll
    for (int mask = 8; mask >= 1; mask >>= 1) {
        #pragma unroll
        for (int i = 0; i < 4; i++) {
            pii[i] += __shfl_xor(pii[i], mask);
            pjj[i] += __shfl_xor(pjj[i], mask);
        }
    }
    if (m == 0) {
        #pragma unroll
        for (int i = 0; i < 4; i++) {
            int row = r0 + quad * 4 + i;
            if (row < N) { ai[row] = pii[i]; aj[row] = pjj[i]; }
        }
    }
}

DEVINL void edge_sd(int e, const int* ei, int& s, int& d) {
    if (e < E) { s = ei[e]; d = ei[E + e]; }
    else       { s = d = e - E; }
}

// ---------- CSR build by dst (once; graph shared across layers) ----------
__global__ __launch_bounds__(256) void k_deg(const int* __restrict__ ei, int* __restrict__ deg) {
    int e = blockIdx.x * 256 + threadIdx.x;
    if (e >= TE) return;
    int s, d; edge_sd(e, ei, s, d);
    atomicAdd(deg + d, 1);
}

__global__ __launch_bounds__(256) void k_scan1(const int* __restrict__ deg, int* __restrict__ bsum) {
    __shared__ int red[256];
    int t = threadIdx.x;
    int v = blockIdx.x * 256 + t;
    red[t] = (v < N) ? deg[v] : 0;
    __syncthreads();
    #pragma unroll
    for (int off = 128; off; off >>= 1) {
        if (t < off) red[t] += red[t + off];
        __syncthreads();
    }
    if (t == 0) bsum[blockIdx.x] = red[0];
}

__global__ __launch_bounds__(256) void k_scan2(const int* __restrict__ bsum,
                                               int* __restrict__ boff, int* __restrict__ row_ptr) {
    __shared__ int sc[256];
    int t = threadIdx.x;
    int v = (t < SCAN_B) ? bsum[t] : 0;
    sc[t] = v;
    __syncthreads();
    #pragma unroll
    for (int off = 1; off < 256; off <<= 1) {
        int add = (t >= off) ? sc[t - off] : 0;
        __syncthreads();
        sc[t] += add;
        __syncthreads();
    }
    if (t < SCAN_B) boff[t] = sc[t] - v;       // exclusive
    if (t == SCAN_B - 1) row_ptr[N] = sc[t];   // total = TE
}

__global__ __launch_bounds__(256) void k_scan3(const int* __restrict__ deg,
                                               const int* __restrict__ boff,
                                               int* __restrict__ row_ptr) {
    __shared__ int sc[256];
    int t = threadIdx.x;
    int v = blockIdx.x * 256 + t;
    int d = (v < N) ? deg[v] : 0;
    sc[t] = d;
    __syncthreads();
    #pragma unroll
    for (int off = 1; off < 256; off <<= 1) {
        int add = (t >= off) ? sc[t - off] : 0;
        __syncthreads();
        sc[t] += add;
        __syncthreads();
    }
    if (v < N) row_ptr[v] = boff[blockIdx.x] + sc[t] - d;
}

// ---------- fill: only src_csr (dst implied by CSR row) ----------
__global__ __launch_bounds__(256) void k_fill(const int* __restrict__ ei,
                                              const int* __restrict__ row_ptr,
                                              int* __restrict__ fill,
                                              int* __restrict__ src_csr) {
    int e = blockIdx.x * 256 + threadIdx.x;
    if (e >= TE) return;
    int s, d; edge_sd(e, ei, s, d);
    int pos = atomicAdd(fill + d, 1);
    src_csr[row_ptr[d] + pos] = s;
}

// ---------- per-edge softmax numerator + denominator, 16-lane group per dst node ----------
__global__ __launch_bounds__(256) void k_edge_soft(const int* __restrict__ row_ptr,
                                                   const int* __restrict__ src_csr,
                                                   const float* __restrict__ ai,
                                                   const float* __restrict__ aj,
                                                   float* __restrict__ alpha,
                                                   float* __restrict__ den) {
    int g = threadIdx.x >> 4, l16 = threadIdx.x & 15;
    int v = blockIdx.x * 16 + g;
    if (v >= N) return;
    int beg = row_ptr[v], end = row_ptr[v + 1];
    float aiv = ai[v];                       // dst-side dot, group-uniform
    for (int idx = beg + l16; idx < end; idx += 16) {
        int s = src_csr[idx];
        float a  = lrelu(aiv + aj[s], 0.2f);
        float ex = expf(a);
        alpha[idx] = ex;
        atomicAdd(den + s, ex);
    }
}

// ---------- per-node reciprocal of denominator ----------
__global__ __launch_bounds__(256) void k_invden(const float* __restrict__ den,
                                                float* __restrict__ invden) {
    int v = blockIdx.x * 256 + threadIdx.x;
    if (v >= N) return;
    invden[v] = 1.0f / (den[v] + 1e-16f);
}

// ---------- aggregation: wave per dst node, pair-gather, bf16 O output ----------
// (R9 NOTE: no per-slot clamping in the hot loop — predication before gathers kills MLP.)
__global__ __launch_bounds__(256) void k_aggregate(const int* __restrict__ row_ptr,
                                                   const int* __restrict__ src_csr,
                                                   const float* __restrict__ alpha,
                                                   const float* __restrict__ invden,
                                                   const uint2* __restrict__ Hu2, // 4 bf16 per uint2
                                                   const float* __restrict__ bvec,
                                                   unsigned short* __restrict__ O16) {
    int wid = threadIdx.x >> 6, lane = threadIdx.x & 63;
    int h = lane >> 5, l32 = lane & 31;
    int v = blockIdx.x * 4 + wid;
    if (v >= N) return;
    int beg = row_ptr[v], end = row_ptr[v + 1];   // non-empty (self loop)
    float a0 = 0.f, a1 = 0.f, a2 = 0.f, a3 = 0.f;
    int idx = beg;
    for (; idx + 8 <= end; idx += 8) {            // 4 pairs = 8 edges
        int   s[4];
        float w[4];
        uint2 u[4];
        #pragma unroll
        for (int t = 0; t < 4; t++) s[t] = src_csr[idx + 2 * t + h];
        #pragma unroll
        for (int t = 0; t < 4; t++) w[t] = alpha[idx + 2 * t + h] * invden[s[t]];
        #pragma unroll
        for (int t = 0; t < 4; t++) u[t] = Hu2[(size_t)s[t] * 32 + l32];
        #pragma unroll
        for (int t = 0; t < 4; t++) {
            a0 += w[t] * bfl(u[t].x);
            a1 += w[t] * bfh(u[t].x);
            a2 += w[t] * bfl(u[t].y);
            a3 += w[t] * bfh(u[t].y);
        }
    }
    for (; idx + 2 <= end; idx += 2) {            // pair tail
        int s = src_csr[idx + h];
        float w = alpha[idx + h] * invden[s];
        uint2 u = Hu2[(size_t)s * 32 + l32];
        a0 += w * bfl(u.x);
        a1 += w * bfh(u.x);
        a2 += w * bfl(u.y);
        a3 += w * bfh(u.y);
    }
    if (idx < end) {                              // single tail: half 1 weight 0
        int s = src_csr[idx];
        float w = (h == 0) ? alpha[idx] * invden[s] : 0.f;
        uint2 u = Hu2[(size_t)s * 32 + l32];
        a0 += w * bfl(u.x);
        a1 += w * bfh(u.x);
        a2 += w * bfl(u.y);
        a3 += w * bfh(u.y);
    }
    a0 += __shfl_xor(a0, 32);
    a1 += __shfl_xor(a1, 32);
    a2 += __shfl_xor(a2, 32);
    a3 += __shfl_xor(a3, 32);
    if (h == 0) {
        float4 b = ((const float4*)bvec)[l32];
        float o0 = fmaxf(a0 + b.x, 0.f);
        float o1 = fmaxf(a1 + b.y, 0.f);
        float o2 = fmaxf(a2 + b.z, 0.f);
        float o3 = fmaxf(a3 + b.w, 0.f);
        uint2 st;
        st.x = (unsigned)f2bf(o0) | ((unsigned)f2bf(o1) << 16);
        st.y = (unsigned)f2bf(o2) | ((unsigned)f2bf(o3) << 16);
        *(uint2*)(O16 + (size_t)v * D + l32 * 4) = st;
    }
}

// ---------- BN column stats on bf16 O: uint2 per thread (4 cols), LDS reduce ----------
// NOTE (R11): last-block finalize via __threadfence() cost ~35 us/layer on gfx950
// (device-scope fence = per-XCD L2 writeback per block). Finalize lives in consumers.
__global__ __launch_bounds__(256) void k_stats(const unsigned short* __restrict__ O16,
                                               float* __restrict__ colsum, float* __restrict__ colsq) {
    int c4 = (threadIdx.x & 31) * 4;   // column base (4 cols per thread)
    int rg = threadIdx.x >> 5;         // row group 0..7
    float s0=0.f,s1=0.f,s2=0.f,s3=0.f,q0=0.f,q1=0.f,q2=0.f,q3=0.f;
    for (int v = blockIdx.x * 8 + rg; v < N; v += gridDim.x * 8) {
        uint2 u = *(const uint2*)(O16 + (size_t)v * D + c4);
        float v0 = bfl(u.x), v1 = bfh(u.x), v2 = bfl(u.y), v3 = bfh(u.y);
        s0 += v0; q0 += v0 * v0;
        s1 += v1; q1 += v1 * v1;
        s2 += v2; q2 += v2 * v2;
        s3 += v3; q3 += v3 * v3;
    }
    __shared__ float ls[8][128], lq[8][128];   // 8 KB
    ls[rg][c4+0]=s0; ls[rg][c4+1]=s1; ls[rg][c4+2]=s2; ls[rg][c4+3]=s3;
    lq[rg][c4+0]=q0; lq[rg][c4+1]=q1; lq[rg][c4+2]=q2; lq[rg][c4+3]=q3;
    __syncthreads();
    if (threadIdx.x < 128) {
        int c = threadIdx.x;
        float s = 0.f, q = 0.f;
        #pragma unroll
        for (int r = 0; r < 8; r++) { s += ls[r][c]; q += lq[r][c]; }
        atomicAdd(colsum + c, s);
        atomicAdd(colsq + c, q);
    }
}

// ---------- decoder ----------
__global__ __launch_bounds__(256) void k_T(const float* __restrict__ P1, const float* __restrict__ P2,
                                           float* __restrict__ T) {
    int t = blockIdx.x * 256 + threadIdx.x;
    if (t >= 128 * 64) return;
    int i = t >> 6, d = t & 63;
    float s = 0.f;
    #pragma unroll 8
    for (int k = 0; k < 64; k++) s += P1[i * 64 + k] * P2[k * 64 + d];
    T[t] = s;
}

__global__ __launch_bounds__(256) void k_M(const float* __restrict__ T, const float* __restrict__ P1,
                                           float* __restrict__ M) {
    int t = blockIdx.x * 256 + threadIdx.x;
    if (t >= 128 * 128) return;
    int i = t >> 7, j = t & 127;
    float s = 0.f;
    #pragma unroll 8
    for (int d = 0; d < 64; d++) s += T[i * 64 + d] * P1[j * 64 + d];
    M[t] = s;
}

__global__ __launch_bounds__(128) void k_pred(const unsigned short* __restrict__ O16,
                                              const float* __restrict__ csum,
                                              const float* __restrict__ csq,
                                              const float* __restrict__ g,
                                              const float* __restrict__ be,
                                              const int* __restrict__ drug,
                                              const float* __restrict__ M,
                                              float* __restrict__ out) {
    int b = blockIdx.x, i = threadIdx.x;
    __shared__ float av[128], bv[128];
    int ia = drug[b * 2] - 1, ib = drug[b * 2 + 1] - 1;
    float mean = csum[i] / (float)N;
    float var  = csq[i] / (float)N - mean * mean;
    float scale = g[i] * rsqrtf(var + 1e-5f);
    float shift = be[i] - mean * scale;
    float ha = __uint_as_float(((unsigned)O16[(size_t)ia * D + i]) << 16);
    float hb = __uint_as_float(((unsigned)O16[(size_t)ib * D + i]) << 16);
    av[i] = lrelu(ha * scale + shift, 0.1f);
    bv[i] = lrelu(hb * scale + shift, 0.1f);
    __syncthreads();
    const float4* M4  = (const float4*)(M + (size_t)i * 128);
    const float4* bv4 = (const float4*)bv;
    float u = 0.f;
    #pragma unroll 8
    for (int j = 0; j < 32; j++) {
        float4 mv = M4[j];
        float4 bb = bv4[j];
        u += mv.x * bb.x + mv.y * bb.y + mv.z * bb.z + mv.w * bb.w;
    }
    float val = av[i] * u;
    #pragma unroll
    for (int off = 32; off; off >>= 1) val += __shfl_down(val, off);
    __shared__ float red[2];
    if ((i & 63) == 0) red[i >> 6] = val;
    __syncthreads();
    if (i == 0) out[b] = red[0] + red[1];
}

extern "C" void kernel_launch(void* const* d_in, const int* in_sizes, int n_in,
                              void* d_out, int out_size, void* d_ws, size_t ws_size,
                              hipStream_t stream) {
    const float* x    = (const float*)d_in[0];
    const int*   ei   = (const int*)  d_in[1];
    const int*   drug = (const int*)  d_in[2];
    const float* W[3]   = {(const float*)d_in[3], (const float*)d_in[8],  (const float*)d_in[13]};
    const float* att[3] = {(const float*)d_in[4], (const float*)d_in[9],  (const float*)d_in[14]};
    const float* bb[3]  = {(const float*)d_in[5], (const float*)d_in[10], (const float*)d_in[15]};
    const float* gg[3]  = {(const float*)d_in[6], (const float*)d_in[11], (const float*)d_in[16]};
    const float* be[3]  = {(const float*)d_in[7], (const float*)d_in[12], (const float*)d_in[17]};
    const float* P1 = (const float*)d_in[18];
    const float* P2 = (const float*)d_in[19];

    float* ws = (float*)d_ws;
    size_t o_H      = 0;                     // bf16 H: N*128 ushorts = N*64 float slots
    size_t o_O      = o_H + (size_t)N * 64;  // bf16 O: N*128 ushorts = N*64 float slots
    size_t o_ai     = o_O + (size_t)N * 64;
    size_t o_aj     = o_ai + N;
    size_t o_den    = o_aj + N;        // [den | colsum | colsq]: one memset per layer
    size_t o_colsum = o_den + N;       // 128
    size_t o_colsq  = o_colsum + 128;  // 128
    size_t o_inv    = o_colsq + 128;
    size_t o_alpha  = o_inv + N;
    size_t o_deg    = o_alpha + TE;    // [deg | fill]: one memset in CSR build
    size_t o_fill   = o_deg + N;       // int
    size_t o_rowptr = o_fill + N;      // int, N+1 (pad 8)
    size_t o_src    = o_rowptr + N + 8;// int, TE
    size_t o_bsum   = o_src + TE;      // int, SCAN_B (pad to 256)
    size_t o_boff   = o_bsum + 256;    // int, SCAN_B (pad to 256)
    size_t o_T      = o_boff + 256;    // 128*64
    size_t o_Mm     = o_T + 128 * 64;  // 128*128
    size_t o_Wb     = o_Mm + 128 * 128;// 3*16384 ushorts = 24576 floats

    unsigned short* Hb16 = (unsigned short*)(ws + o_H);
    uint2*          Hu2  = (uint2*)(ws + o_H);
    unsigned short* O16  = (unsigned short*)(ws + o_O);
    float*    ai    = ws + o_ai;
    float*    aj    = ws + o_aj;
    float*    den   = ws + o_den;
    float*    csum  = ws + o_colsum;
    float*    csq   = ws + o_colsq;
    float*    inv   = ws + o_inv;
    float*    alpha = ws + o_alpha;
    int*      deg   = (int*)(ws + o_deg);
    int*      fill  = (int*)(ws + o_fill);
    int*      rowp  = (int*)(ws + o_rowptr);
    int*      srcc  = (int*)(ws + o_src);
    int*      bsum  = (int*)(ws + o_bsum);
    int*      boff  = (int*)(ws + o_boff);
    float*    Tm    = ws + o_T;
    float*    Mm    = ws + o_Mm;
    unsigned short* Wb = (unsigned short*)(ws + o_Wb);

    const int EB = (TE + 255) / 256;
    const int NB4  = (N + 3) / 4;
    const int NB16 = (N + 15) / 16;

    // ---- CSR by dst ----
    hipMemsetAsync(deg, 0, (size_t)2 * N * 4, stream);   // deg + fill
    k_deg<<<EB, 256, 0, stream>>>(ei, deg);
    k_scan1<<<SCAN_B, 256, 0, stream>>>(deg, bsum);
    k_scan2<<<1, 256, 0, stream>>>(bsum, boff, rowp);
    k_scan3<<<SCAN_B, 256, 0, stream>>>(deg, boff, rowp);
    k_fill<<<EB, 256, 0, stream>>>(ei, rowp, fill, srcc);

    // ---- W bf16 copies (one launch) ----
    k_wb3<<<192, 256, 0, stream>>>(W[0], W[1], W[2], Wb);

    // ---- 3 GAT layers ----
    for (int l = 0; l < 3; l++) {
        // gemm reads previous layer's colsum/colsq (l>0) — memset AFTER gemm.
        k_gemm<<<GEMM_B, 256, 0, stream>>>(x, O16, Wb + l * 16384, Hb16, att[l],
                                           ai, aj, csum, csq, gg[l == 0 ? 0 : l - 1],
                                           be[l == 0 ? 0 : l - 1], l > 0 ? 1 : 0);
        hipMemsetAsync(den, 0, (size_t)(N + 256) * 4, stream);  // den + colsum + colsq
        k_edge_soft<<<NB16, 256, 0, stream>>>(rowp, srcc, ai, aj, alpha, den);
        k_invden<<<SCAN_B, 256, 0, stream>>>(den, inv);
        k_aggregate<<<NB4, 256, 0, stream>>>(rowp, srcc, alpha, inv, Hu2, bb[l], O16);
        k_stats<<<256, 256, 0, stream>>>(O16, csum, csq);
    }

    // ---- decoder (BN finalize for layer 3 is inlined in k_pred) ----
    k_T<<<32, 256, 0, stream>>>(P1, P2, Tm);
    k_M<<<64, 256, 0, stream>>>(Tm, P1, Mm);
    k_pred<<<1024, 128, 0, stream>>>(O16, csum, csq, gg[2], be[2], drug, Mm, (float*)d_out);
}